// Round 1
// baseline (1205.217 us; speedup 1.0000x reference)
//
#include <hip/hip_runtime.h>
#include <math.h>

#define NBATCH 8
#define NPTS   1024
#define KNN    8
#define CC     128
#define HD_    128
#define TED_   128
#define TEC_   64
#define RH     32
#define NL     4

struct MapArg { int m[8]; };

// ---------------------------------------------------------------- temb
__global__ __launch_bounds__(128) void k_temb(
    const float* __restrict__ t, const float* __restrict__ Wt1,
    const float* __restrict__ bt1, const float* __restrict__ Wt2,
    const float* __restrict__ bt2, const float* __restrict__ Win0,
    const float* __restrict__ bin0, float* __restrict__ pre0)
{
  int b = blockIdx.x;
  int tid = threadIdx.x;
  __shared__ float e128[TED_];
  __shared__ float h1[TED_];
  __shared__ float te[TEC_];
  float tv = t[b];
  if (tid < 64) {
    float fr = expf((-9.210340371976184f * (float)tid) * 0.015625f);
    float em = tv * fr;
    e128[tid]      = sinf(em);
    e128[tid + 64] = cosf(em);
  }
  __syncthreads();
  {
    float acc = bt1[tid];
    for (int i = 0; i < TED_; ++i) acc += e128[i] * Wt1[i * TED_ + tid];
    h1[tid] = acc / (1.0f + expf(-acc));
  }
  __syncthreads();
  if (tid < TEC_) {
    float acc = bt2[tid];
    for (int j = 0; j < TED_; ++j) acc += h1[j] * Wt2[j * TEC_ + tid];
    te[tid] = acc;
  }
  __syncthreads();
  {
    float acc = bin0[tid];
    for (int i = 0; i < TEC_; ++i) acc += te[i] * Win0[i * CC + tid];
    pre0[b * CC + tid] = acc;
  }
}

// ---------------------------------------------------------------- init f0/f1
__global__ __launch_bounds__(256) void k_init(
    const float* __restrict__ x, const float* __restrict__ Win0,
    const float* __restrict__ Win1, const float* __restrict__ pre0,
    float* __restrict__ f0, float* __restrict__ f1)
{
  int node = blockIdx.x * 2 + (threadIdx.x >> 7);
  int c = threadIdx.x & 127;
  int b = node >> 10;
  float x0 = x[node * 3 + 0], x1 = x[node * 3 + 1], x2 = x[node * 3 + 2];
  float acc = pre0[b * CC + c]
            + x0 * Win0[(TEC_ + 0) * CC + c]
            + x1 * Win0[(TEC_ + 1) * CC + c]
            + x2 * Win0[(TEC_ + 2) * CC + c];
  f0[(size_t)node * CC + c] = acc;
  float w1 = Win1[c];
  f1[((size_t)node * 3 + 0) * CC + c] = x0 * w1;
  f1[((size_t)node * 3 + 1) * CC + c] = x1 * w1;
  f1[((size_t)node * 3 + 2) * CC + c] = x2 * w1;
}

// ---------------------------------------------------------------- knn
__global__ __launch_bounds__(256) void k_knn(
    const float* __restrict__ x, int* __restrict__ idx,
    float* __restrict__ rhat, float* __restrict__ rl)
{
  int b = blockIdx.x >> 2;
  int tile = blockIdx.x & 3;
  int tid = threadIdx.x;
  __shared__ float xs[NPTS * 3];
  for (int i = tid; i < NPTS * 3; i += 256) xs[i] = x[(size_t)b * NPTS * 3 + i];
  __syncthreads();
  int n = tile * 256 + tid;
  float qx = xs[n * 3 + 0], qy = xs[n * 3 + 1], qz = xs[n * 3 + 2];
  float bd[KNN];
  int   bi[KNN];
  #pragma unroll
  for (int k = 0; k < KNN; ++k) { bd[k] = 3.0e38f; bi[k] = 0; }
  for (int j = 0; j < NPTS; ++j) {
    float dx = qx - xs[j * 3 + 0];
    float dy = qy - xs[j * 3 + 1];
    float dz = qz - xs[j * 3 + 2];
    // match JAX exactly: no fma contraction, ((dx2+dy2)+dz2)
    float s = __fadd_rn(__fadd_rn(__fmul_rn(dx, dx), __fmul_rn(dy, dy)),
                        __fmul_rn(dz, dz));
    if (j == n) s = 1.0e9f;
    if (s < bd[KNN - 1]) {
      int pos = KNN - 1;
      #pragma unroll
      for (int q = KNN - 2; q >= 0; --q) {
        if (bd[q] > s) { bd[q + 1] = bd[q]; bi[q + 1] = bi[q]; pos = q; }
      }
      bd[pos] = s; bi[pos] = j;
    }
  }
  size_t base = ((size_t)b * NPTS + n) * KNN;
  #pragma unroll
  for (int k = 0; k < KNN; ++k) {
    int j = bi[k];
    idx[base + k] = j;
    float rx = xs[j * 3 + 0] - qx;
    float ry = xs[j * 3 + 1] - qy;
    float rz = xs[j * 3 + 2] - qz;
    float rr2 = rx * rx + ry * ry + rz * rz + 1e-8f;
    float r = sqrtf(rr2);
    rl[base + k] = r;
    rhat[(base + k) * 3 + 0] = rx / r;
    rhat[(base + k) * 3 + 1] = ry / r;
    rhat[(base + k) * 3 + 2] = rz / r;
  }
}

// ---------------------------------------------------------------- proj GEMM
// P[row, m*128+e] = sum_c A[row,c] * Wl[map[m]][c][e]
__global__ __launch_bounds__(256) void k_proj(
    const float* __restrict__ A, const float* __restrict__ Wl,
    MapArg map, float* __restrict__ P, int ldP)
{
  int mblk = blockIdx.y >> 1;
  int coff = (blockIdx.y & 1) * 64;
  const float* W = Wl + (size_t)map.m[mblk] * (CC * HD_) + coff;
  int rowBase = blockIdx.x * 64;
  int tid = threadIdx.x;
  int tx = tid & 15, ty = tid >> 4;
  __shared__ float As[64 * 65];   // [m][k], pad 65
  __shared__ float Ws[64 * 68];   // [k][c], pad 68 (16B aligned rows)
  float acc[4][4];
  #pragma unroll
  for (int i = 0; i < 4; ++i)
    #pragma unroll
    for (int j = 0; j < 4; ++j) acc[i][j] = 0.0f;

  for (int kk = 0; kk < CC; kk += 64) {
    #pragma unroll
    for (int i = 0; i < 4; ++i) {
      int r = (tid >> 4) + i * 16;
      int kq = (tid & 15) * 4;
      float4 av = *(const float4*)&A[(size_t)(rowBase + r) * CC + kk + kq];
      As[r * 65 + kq + 0] = av.x;
      As[r * 65 + kq + 1] = av.y;
      As[r * 65 + kq + 2] = av.z;
      As[r * 65 + kq + 3] = av.w;
    }
    #pragma unroll
    for (int i = 0; i < 4; ++i) {
      int kr = (tid >> 4) + i * 16;
      int cq = (tid & 15) * 4;
      float4 wv = *(const float4*)&W[(size_t)(kk + kr) * HD_ + cq];
      *(float4*)&Ws[kr * 68 + cq] = wv;
    }
    __syncthreads();
    #pragma unroll 16
    for (int k = 0; k < 64; ++k) {
      float a0 = As[(ty * 4 + 0) * 65 + k];
      float a1 = As[(ty * 4 + 1) * 65 + k];
      float a2 = As[(ty * 4 + 2) * 65 + k];
      float a3 = As[(ty * 4 + 3) * 65 + k];
      float4 w = *(float4*)&Ws[k * 68 + tx * 4];
      acc[0][0] += a0 * w.x; acc[0][1] += a0 * w.y; acc[0][2] += a0 * w.z; acc[0][3] += a0 * w.w;
      acc[1][0] += a1 * w.x; acc[1][1] += a1 * w.y; acc[1][2] += a1 * w.z; acc[1][3] += a1 * w.w;
      acc[2][0] += a2 * w.x; acc[2][1] += a2 * w.y; acc[2][2] += a2 * w.z; acc[2][3] += a2 * w.w;
      acc[3][0] += a3 * w.x; acc[3][1] += a3 * w.y; acc[3][2] += a3 * w.z; acc[3][3] += a3 * w.w;
    }
    __syncthreads();
  }
  int colBase = mblk * 128 + coff;
  #pragma unroll
  for (int i = 0; i < 4; ++i) {
    float4 o;
    o.x = acc[i][0]; o.y = acc[i][1]; o.z = acc[i][2]; o.w = acc[i][3];
    *(float4*)&P[(size_t)(rowBase + ty * 4 + i) * ldP + colBase + tx * 4] = o;
  }
}

// ---------------------------------------------------------------- combine
__global__ __launch_bounds__(128) void k_combine(
    const float* __restrict__ P0, const float* __restrict__ P1,
    const int* __restrict__ idx, const float* __restrict__ rhat,
    const float* __restrict__ rl,
    const float* __restrict__ Wr1, const float* __restrict__ br1,
    const float* __restrict__ Wr2, const float* __restrict__ br2,
    const float* __restrict__ Wo, const float* __restrict__ bo,
    float* __restrict__ f0, float* __restrict__ f1,
    int nodeBase, int layer)
{
  const int t = threadIdx.x;
  const int h = t >> 4;
  const int node = nodeBase + blockIdx.x;

  __shared__ float rn_s[KNN][80];
  __shared__ float hid_s[KNN][RH];
  __shared__ float rh_s[KNN][3];
  __shared__ float rl_s[KNN];
  __shared__ float o0_s[CC];
  __shared__ float o1_s[3 * CC];
  __shared__ float wt_s[32 * CC];

  if (t < KNN * 3) rh_s[t / 3][t % 3] = rhat[(size_t)node * KNN * 3 + t];
  if (t >= 32 && t < 32 + KNN) rl_s[t - 32] = rl[(size_t)node * KNN + (t - 32)];
  __syncthreads();

  const float* wr1 = Wr1 + layer * RH;
  const float* wb1 = br1 + layer * RH;
  #pragma unroll
  for (int u = 0; u < 2; ++u) {
    int f = u * 128 + t;
    int k = f >> 5, i = f & 31;
    float z = rl_s[k] * wr1[i] + wb1[i];
    hid_s[k][i] = z / (1.0f + expf(-z));
  }
  __syncthreads();
  const float* wr2 = Wr2 + layer * RH * 80;
  const float* wb2 = br2 + layer * 80;
  #pragma unroll
  for (int u = 0; u < 5; ++u) {
    int f = u * 128 + t;
    int k = f / 80, col = f - k * 80;
    float acc = wb2[col];
    #pragma unroll
    for (int i = 0; i < RH; ++i) acc += hid_s[k][i] * wr2[i * 80 + col];
    rn_s[k][col] = acc;
  }
  __syncthreads();

  const float* p0n = P0 + (size_t)blockIdx.x * 640;
  const size_t p1row = (size_t)blockIdx.x * 3 * 896;
  float q0  = p0n[t];
  float q1x = P1[p1row + t];
  float q1y = P1[p1row + 896 + t];
  float q1z = P1[p1row + 1792 + t];

  float logit[KNN];
  float v0k[KNN], v1xk[KNN], v1yk[KNN], v1zk[KNN];
  const float inv_scale = 0.17677669529663687f;  // 1/sqrt(32)

  #pragma unroll
  for (int k = 0; k < KNN; ++k) {
    int jj = idx[(size_t)node * KNN + k];
    int jl = ((node >> 10) << 10) + jj - nodeBase;
    const float* g0 = P0 + (size_t)jl * 640;
    const float* g1 = P1 + (size_t)jl * 3 * 896;
    float rx = rh_s[k][0], ry = rh_s[k][1], rz = rh_s[k][2];

    float G02 = g0[128 + t], G04 = g0[256 + t], G07 = g0[384 + t], G09 = g0[512 + t];
    float G13x = g1[128 + t], G13y = g1[896 + 128 + t], G13z = g1[1792 + 128 + t];
    float G15x = g1[256 + t], G15y = g1[896 + 256 + t], G15z = g1[1792 + 256 + t];
    float G16x = g1[384 + t], G16y = g1[896 + 384 + t], G16z = g1[1792 + 384 + t];
    float G18x = g1[512 + t], G18y = g1[896 + 512 + t], G18z = g1[1792 + 512 + t];
    float G1Ax = g1[640 + t], G1Ay = g1[896 + 640 + t], G1Az = g1[1792 + 640 + t];
    float G1Bx = g1[768 + t], G1By = g1[896 + 768 + t], G1Bz = g1[1792 + 768 + t];

    float DP3 = G13x * rx + G13y * ry + G13z * rz;
    float DP6 = G16x * rx + G16y * ry + G16z * rz;
    float DP8 = G18x * rx + G18y * ry + G18z * rz;
    float DPB = G1Bx * rx + G1By * ry + G1Bz * rz;

    const float* rnh = &rn_s[k][h * 10];
    float r0 = rnh[0], r1 = rnh[1], r2 = rnh[2], r3 = rnh[3], r4 = rnh[4];
    float r5 = rnh[5], r6 = rnh[6], r7 = rnh[7], r8 = rnh[8], r9 = rnh[9];

    float k0  = G02 * r0 + DP3 * r1;
    float k1x = G04 * rx * r2 + G15x * r3 + (3.0f * rx * DP6 - G16x) * r4;
    float k1y = G04 * ry * r2 + G15y * r3 + (3.0f * ry * DP6 - G16y) * r4;
    float k1z = G04 * rz * r2 + G15z * r3 + (3.0f * rz * DP6 - G16z) * r4;
    float v0  = G07 * r5 + DP8 * r6;
    float v1x = G09 * rx * r7 + G1Ax * r8 + (3.0f * rx * DPB - G1Bx) * r9;
    float v1y = G09 * ry * r7 + G1Ay * r8 + (3.0f * ry * DPB - G1By) * r9;
    float v1z = G09 * rz * r7 + G1Az * r8 + (3.0f * rz * DPB - G1Bz) * r9;

    float pl = q0 * k0 + q1x * k1x + q1y * k1y + q1z * k1z;
    pl += __shfl_xor(pl, 1, 16);
    pl += __shfl_xor(pl, 2, 16);
    pl += __shfl_xor(pl, 4, 16);
    pl += __shfl_xor(pl, 8, 16);
    logit[k] = pl * inv_scale;
    v0k[k] = v0; v1xk[k] = v1x; v1yk[k] = v1y; v1zk[k] = v1z;
  }

  float mx = logit[0];
  #pragma unroll
  for (int k = 1; k < KNN; ++k) mx = fmaxf(mx, logit[k]);
  float ssum = 0.0f;
  float wgt[KNN];
  #pragma unroll
  for (int k = 0; k < KNN; ++k) { wgt[k] = expf(logit[k] - mx); ssum += wgt[k]; }
  float invs = 1.0f / ssum;
  float o0 = 0.0f, o1x = 0.0f, o1y = 0.0f, o1z = 0.0f;
  #pragma unroll
  for (int k = 0; k < KNN; ++k) {
    float a = wgt[k] * invs;
    o0 += a * v0k[k]; o1x += a * v1xk[k]; o1y += a * v1yk[k]; o1z += a * v1zk[k];
  }
  o0_s[t] = o0;
  o1_s[t] = o1x; o1_s[CC + t] = o1y; o1_s[2 * CC + t] = o1z;

  float acc0 = f0[(size_t)node * CC + t] + bo[(layer * 2 + 0) * CC + t];
  float b1   = bo[(layer * 2 + 1) * CC + t];
  float a1x = f1[((size_t)node * 3 + 0) * CC + t] + b1;
  float a1y = f1[((size_t)node * 3 + 1) * CC + t] + b1;
  float a1z = f1[((size_t)node * 3 + 2) * CC + t] + b1;
  __syncthreads();

  const float* wo0 = Wo + (size_t)(layer * 2 + 0) * HD_ * CC;
  #pragma unroll
  for (int ch = 0; ch < 4; ++ch) {
    #pragma unroll
    for (int u = 0; u < 8; ++u) {
      int f4 = u * 128 + t;
      int e = f4 >> 5;
      int cq = (f4 & 31) * 4;
      *(float4*)&wt_s[e * CC + cq] = *(const float4*)&wo0[(size_t)(ch * 32 + e) * CC + cq];
    }
    __syncthreads();
    #pragma unroll
    for (int e = 0; e < 32; ++e) acc0 += o0_s[ch * 32 + e] * wt_s[e * CC + t];
    __syncthreads();
  }
  const float* wo1 = Wo + (size_t)(layer * 2 + 1) * HD_ * CC;
  #pragma unroll
  for (int ch = 0; ch < 4; ++ch) {
    #pragma unroll
    for (int u = 0; u < 8; ++u) {
      int f4 = u * 128 + t;
      int e = f4 >> 5;
      int cq = (f4 & 31) * 4;
      *(float4*)&wt_s[e * CC + cq] = *(const float4*)&wo1[(size_t)(ch * 32 + e) * CC + cq];
    }
    __syncthreads();
    #pragma unroll
    for (int e = 0; e < 32; ++e) {
      float w_ = wt_s[e * CC + t];
      int eo = ch * 32 + e;
      a1x += o1_s[eo] * w_;
      a1y += o1_s[CC + eo] * w_;
      a1z += o1_s[2 * CC + eo] * w_;
    }
    __syncthreads();
  }
  f0[(size_t)node * CC + t] = acc0;
  f1[((size_t)node * 3 + 0) * CC + t] = a1x;
  f1[((size_t)node * 3 + 1) * CC + t] = a1y;
  f1[((size_t)node * 3 + 2) * CC + t] = a1z;
}

// ---------------------------------------------------------------- final out
__global__ __launch_bounds__(256) void k_out(
    const float* __restrict__ f1, const float* __restrict__ Wout,
    const float* __restrict__ bout, float* __restrict__ out)
{
  int i = blockIdx.x * 256 + threadIdx.x;  // < 24576 rows = node*3+v
  int v = i % 3;
  const float* row = f1 + (size_t)i * CC;
  const float* w = Wout + v * CC;
  float acc = 0.0f;
  #pragma unroll
  for (int c = 0; c < CC; c += 4) {
    float4 fv = *(const float4*)&row[c];
    float4 wv = *(const float4*)&w[c];
    acc += fv.x * wv.x + fv.y * wv.y + fv.z * wv.z + fv.w * wv.w;
  }
  out[i] = acc + bout[v];
}

// ---------------------------------------------------------------- host
extern "C" void kernel_launch(void* const* d_in, const int* in_sizes, int n_in,
                              void* d_out, int out_size, void* d_ws, size_t ws_size,
                              hipStream_t stream) {
  const float* x    = (const float*)d_in[0];
  const float* t    = (const float*)d_in[2];
  const float* Wt1  = (const float*)d_in[3];
  const float* bt1  = (const float*)d_in[4];
  const float* Wt2  = (const float*)d_in[5];
  const float* bt2  = (const float*)d_in[6];
  const float* Win0 = (const float*)d_in[7];
  const float* bin0 = (const float*)d_in[8];
  const float* Win1 = (const float*)d_in[9];
  const float* Wqkv = (const float*)d_in[10];
  const float* Wr1  = (const float*)d_in[11];
  const float* br1  = (const float*)d_in[12];
  const float* Wr2  = (const float*)d_in[13];
  const float* br2  = (const float*)d_in[14];
  const float* Wo   = (const float*)d_in[15];
  const float* bo   = (const float*)d_in[16];
  const float* Wout = (const float*)d_in[17];
  const float* bout = (const float*)d_in[18];
  float* out = (float*)d_out;

  char* wsb = (char*)d_ws;
  size_t off = 0;
  auto alloc = [&](size_t bytes) -> void* {
    void* p = wsb + off;
    off = (off + bytes + 255) & ~(size_t)255;
    return p;
  };
  const int totalNodes = NBATCH * NPTS;  // 8192
  float* pre0 = (float*)alloc((size_t)NBATCH * CC * 4);
  float* f0   = (float*)alloc((size_t)totalNodes * CC * 4);
  float* f1   = (float*)alloc((size_t)totalNodes * 3 * CC * 4);
  int*   idx  = (int*)alloc((size_t)totalNodes * KNN * 4);
  float* rhat = (float*)alloc((size_t)totalNodes * KNN * 3 * 4);
  float* rl   = (float*)alloc((size_t)totalNodes * KNN * 4);
  size_t fixedBytes = off;
  size_t perBatchP = (size_t)NPTS * (640 + 2688) * 4;
  int nbg = 8;
  while (nbg > 1 && fixedBytes + (size_t)nbg * perBatchP + 4096 > ws_size) nbg >>= 1;
  float* P0 = (float*)alloc((size_t)nbg * NPTS * 640 * 4);
  float* P1 = (float*)alloc((size_t)nbg * NPTS * 2688 * 4);

  k_temb<<<NBATCH, 128, 0, stream>>>(t, Wt1, bt1, Wt2, bt2, Win0, bin0, pre0);
  k_init<<<totalNodes / 2, 256, 0, stream>>>(x, Win0, Win1, pre0, f0, f1);
  k_knn<<<NBATCH * (NPTS / 256), 256, 0, stream>>>(x, idx, rhat, rl);

  MapArg map0; map0.m[0] = 0; map0.m[1] = 2; map0.m[2] = 4; map0.m[3] = 7; map0.m[4] = 9;
  map0.m[5] = 0; map0.m[6] = 0; map0.m[7] = 0;
  MapArg map1; map1.m[0] = 1; map1.m[1] = 3; map1.m[2] = 5; map1.m[3] = 6;
  map1.m[4] = 8; map1.m[5] = 10; map1.m[6] = 11; map1.m[7] = 0;

  for (int g = 0; g < NBATCH / nbg; ++g) {
    int nodeBase = g * nbg * NPTS;
    int nodes = nbg * NPTS;
    for (int l = 0; l < NL; ++l) {
      const float* Wl = Wqkv + (size_t)l * 12 * CC * HD_;
      k_proj<<<dim3(nodes / 64, 10), 256, 0, stream>>>(
          f0 + (size_t)nodeBase * CC, Wl, map0, P0, 640);
      k_proj<<<dim3(nodes * 3 / 64, 14), 256, 0, stream>>>(
          f1 + (size_t)nodeBase * 3 * CC, Wl, map1, P1, 896);
      k_combine<<<nodes, 128, 0, stream>>>(
          P0, P1, idx, rhat, rl, Wr1, br1, Wr2, br2, Wo, bo, f0, f1, nodeBase, l);
    }
  }
  k_out<<<(totalNodes * 3) / 256, 256, 0, stream>>>(f1, Wout, bout, out);
}

// Round 2
// 1116.289 us; speedup vs baseline: 1.0797x; 1.0797x over previous
//
#include <hip/hip_runtime.h>
#include <math.h>

#define NBATCH 8
#define NPTS   1024
#define KNN    8
#define CC     128
#define HD_    128
#define TED_   128
#define TEC_   64
#define RH     32
#define NL     4

// ---------------------------------------------------------------- temb
__global__ __launch_bounds__(128) void k_temb(
    const float* __restrict__ t, const float* __restrict__ Wt1,
    const float* __restrict__ bt1, const float* __restrict__ Wt2,
    const float* __restrict__ bt2, const float* __restrict__ Win0,
    const float* __restrict__ bin0, float* __restrict__ pre0)
{
  int b = blockIdx.x;
  int tid = threadIdx.x;
  __shared__ float e128[TED_];
  __shared__ float h1[TED_];
  __shared__ float te[TEC_];
  float tv = t[b];
  if (tid < 64) {
    float fr = expf((-9.210340371976184f * (float)tid) * 0.015625f);
    float em = tv * fr;
    e128[tid]      = sinf(em);
    e128[tid + 64] = cosf(em);
  }
  __syncthreads();
  {
    float acc = bt1[tid];
    for (int i = 0; i < TED_; ++i) acc += e128[i] * Wt1[i * TED_ + tid];
    h1[tid] = acc / (1.0f + expf(-acc));
  }
  __syncthreads();
  if (tid < TEC_) {
    float acc = bt2[tid];
    for (int j = 0; j < TED_; ++j) acc += h1[j] * Wt2[j * TEC_ + tid];
    te[tid] = acc;
  }
  __syncthreads();
  {
    float acc = bin0[tid];
    for (int i = 0; i < TEC_; ++i) acc += te[i] * Win0[i * CC + tid];
    pre0[b * CC + tid] = acc;
  }
}

// ---------------------------------------------------------------- init f0/f1
__global__ __launch_bounds__(256) void k_init(
    const float* __restrict__ x, const float* __restrict__ Win0,
    const float* __restrict__ Win1, const float* __restrict__ pre0,
    float* __restrict__ f0, float* __restrict__ f1)
{
  int node = blockIdx.x * 2 + (threadIdx.x >> 7);
  int c = threadIdx.x & 127;
  int b = node >> 10;
  float x0 = x[node * 3 + 0], x1 = x[node * 3 + 1], x2 = x[node * 3 + 2];
  float acc = pre0[b * CC + c]
            + x0 * Win0[(TEC_ + 0) * CC + c]
            + x1 * Win0[(TEC_ + 1) * CC + c]
            + x2 * Win0[(TEC_ + 2) * CC + c];
  f0[(size_t)node * CC + c] = acc;
  float w1 = Win1[c];
  f1[((size_t)node * 3 + 0) * CC + c] = x0 * w1;
  f1[((size_t)node * 3 + 1) * CC + c] = x1 * w1;
  f1[((size_t)node * 3 + 2) * CC + c] = x2 * w1;
}

// ---------------------------------------------------------------- knn v2
// 8 threads per query; packed (dist_bits<<32)|j keys reproduce top_k ordering
// (ascending dist, tie -> lower index) exactly.
__global__ __launch_bounds__(256) void k_knn(
    const float* __restrict__ x, int* __restrict__ idx,
    float* __restrict__ rhat, float* __restrict__ rl)
{
  const int b    = blockIdx.x >> 5;    // 32 blocks per batch
  const int tile = blockIdx.x & 31;    // 32 queries per block
  const int tid  = threadIdx.x;
  const int qg   = tid >> 3;           // 0..31 query within block
  const int sub  = tid & 7;            // 0..7 scan slice

  __shared__ float xs[NPTS * 3];
  __shared__ unsigned long long keys[32][64];
  __shared__ unsigned long long res[32][KNN];

  for (int i = tid; i < NPTS * 3; i += 256) xs[i] = x[(size_t)b * NPTS * 3 + i];
  __syncthreads();

  const int n = tile * 32 + qg;
  const float qx = xs[n * 3 + 0], qy = xs[n * 3 + 1], qz = xs[n * 3 + 2];

  unsigned long long bd[KNN];
  #pragma unroll
  for (int k = 0; k < KNN; ++k) bd[k] = ~0ull;

  const int j0 = sub * 128;
  for (int j = j0; j < j0 + 128; ++j) {
    float dx = qx - xs[j * 3 + 0];
    float dy = qy - xs[j * 3 + 1];
    float dz = qz - xs[j * 3 + 2];
    float s = __fadd_rn(__fadd_rn(__fmul_rn(dx, dx), __fmul_rn(dy, dy)),
                        __fmul_rn(dz, dz));
    if (j == n) s = 1.0e9f;
    unsigned long long key =
        ((unsigned long long)__float_as_uint(s) << 32) | (unsigned int)j;
    if (key < bd[KNN - 1]) {
      bd[KNN - 1] = key;
      #pragma unroll
      for (int q = KNN - 1; q > 0; --q) {
        if (bd[q] < bd[q - 1]) {
          unsigned long long tmp = bd[q]; bd[q] = bd[q - 1]; bd[q - 1] = tmp;
        }
      }
    }
  }
  #pragma unroll
  for (int k = 0; k < KNN; ++k) keys[qg][sub * KNN + k] = bd[k];
  __syncthreads();

  if (sub == 0) {
    unsigned long long m[KNN];
    #pragma unroll
    for (int k = 0; k < KNN; ++k) m[k] = ~0ull;
    for (int i = 0; i < 64; ++i) {
      unsigned long long key = keys[qg][i];
      if (key < m[KNN - 1]) {
        m[KNN - 1] = key;
        #pragma unroll
        for (int q = KNN - 1; q > 0; --q) {
          if (m[q] < m[q - 1]) {
            unsigned long long tmp = m[q]; m[q] = m[q - 1]; m[q - 1] = tmp;
          }
        }
      }
    }
    #pragma unroll
    for (int k = 0; k < KNN; ++k) res[qg][k] = m[k];
  }
  __syncthreads();

  if (sub == 0) {
    size_t base = ((size_t)b * NPTS + n) * KNN;
    #pragma unroll
    for (int k = 0; k < KNN; ++k) {
      int j = (int)(res[qg][k] & 0xffffffffu);
      idx[base + k] = j;
      float rx = xs[j * 3 + 0] - qx;
      float ry = xs[j * 3 + 1] - qy;
      float rz = xs[j * 3 + 2] - qz;
      float rr2 = rx * rx + ry * ry + rz * rz + 1e-8f;
      float r = sqrtf(rr2);
      rl[base + k] = r;
      rhat[(base + k) * 3 + 0] = rx / r;
      rhat[(base + k) * 3 + 1] = ry / r;
      rhat[(base + k) * 3 + 2] = rz / r;
    }
  }
}

// ---------------------------------------------------------------- 128x128x128 fp32 GEMM body
// A: row-major [*][128]; W: [128][128] (k stride 128). acc 8x8 per thread.
#define GEMM_BODY(A_, ROWBASE_, W_)                                           \
  int tid = threadIdx.x;                                                      \
  int tx = tid & 15, ty = tid >> 4;                                           \
  __shared__ float As[32][132];                                               \
  __shared__ float Ws[32][128];                                               \
  float acc[8][8] = {};                                                       \
  for (int kk = 0; kk < 128; kk += 32) {                                      \
    {                                                                         \
      int row = tid >> 1;                                                     \
      int kq = (tid & 1) * 16;                                                \
      const float* ap = (A_) + (size_t)((ROWBASE_) + row) * 128 + kk + kq;    \
      _Pragma("unroll")                                                       \
      for (int q = 0; q < 4; ++q) {                                           \
        float4 v = *(const float4*)(ap + q * 4);                              \
        As[kq + q * 4 + 0][row] = v.x;                                        \
        As[kq + q * 4 + 1][row] = v.y;                                        \
        As[kq + q * 4 + 2][row] = v.z;                                        \
        As[kq + q * 4 + 3][row] = v.w;                                        \
      }                                                                       \
    }                                                                         \
    {                                                                         \
      int kr = tid >> 3;                                                      \
      int cq = (tid & 7) * 16;                                                \
      const float* wp = (W_) + (size_t)(kk + kr) * 128 + cq;                  \
      _Pragma("unroll")                                                       \
      for (int q = 0; q < 4; ++q)                                             \
        *(float4*)&Ws[kr][cq + q * 4] = *(const float4*)(wp + q * 4);         \
    }                                                                         \
    __syncthreads();                                                          \
    _Pragma("unroll 4")                                                       \
    for (int k = 0; k < 32; ++k) {                                            \
      float a[8], bb[8];                                                      \
      *(float4*)&a[0] = *(float4*)&As[k][ty * 4];                             \
      *(float4*)&a[4] = *(float4*)&As[k][64 + ty * 4];                        \
      *(float4*)&bb[0] = *(float4*)&Ws[k][tx * 4];                            \
      *(float4*)&bb[4] = *(float4*)&Ws[k][64 + tx * 4];                       \
      _Pragma("unroll")                                                       \
      for (int i = 0; i < 8; ++i) {                                           \
        _Pragma("unroll")                                                     \
        for (int j = 0; j < 8; ++j) acc[i][j] += a[i] * bb[j];                \
      }                                                                       \
    }                                                                         \
    __syncthreads();                                                          \
  }

// ---------------------------------------------------------------- proj (P0+P1 in one launch)
__global__ __launch_bounds__(256) void k_proj_all(
    const float* __restrict__ f0, const float* __restrict__ f1,
    const float* __restrict__ Wl, float* __restrict__ P0,
    float* __restrict__ P1, int nb0)
{
  int z = blockIdx.x;
  const float* A; const float* W; float* P; int ldP, colBase, rowBase;
  if (z < nb0 * 5) {
    const int map0[5] = {0, 2, 4, 7, 9};
    int m = z / nb0, rb = z - m * nb0;
    A = f0; rowBase = rb * 128;
    W = Wl + (size_t)map0[m] * (CC * HD_);
    P = P0; ldP = 640; colBase = m * 128;
  } else {
    z -= nb0 * 5;
    int nb1 = nb0 * 3;
    const int map1[7] = {1, 3, 5, 6, 8, 10, 11};
    int m = z / nb1, rb = z - m * nb1;
    A = f1; rowBase = rb * 128;
    W = Wl + (size_t)map1[m] * (CC * HD_);
    P = P1; ldP = 896; colBase = m * 128;
  }
  GEMM_BODY(A, rowBase, W)
  #pragma unroll
  for (int i = 0; i < 8; ++i) {
    int r = rowBase + ((i < 4) ? (ty * 4 + i) : (64 + ty * 4 + i - 4));
    float* op = P + (size_t)r * ldP + colBase;
    float4 o0v; o0v.x = acc[i][0]; o0v.y = acc[i][1]; o0v.z = acc[i][2]; o0v.w = acc[i][3];
    float4 o1v; o1v.x = acc[i][4]; o1v.y = acc[i][5]; o1v.z = acc[i][6]; o1v.w = acc[i][7];
    *(float4*)(op + tx * 4) = o0v;
    *(float4*)(op + 64 + tx * 4) = o1v;
  }
}

// ---------------------------------------------------------------- Wo GEMM with residual+bias
__global__ __launch_bounds__(256) void k_wo(
    const float* __restrict__ o0, const float* __restrict__ o1,
    const float* __restrict__ Wo_l, const float* __restrict__ bo_l,
    float* __restrict__ f0, float* __restrict__ f1, int nb0)
{
  int z = blockIdx.x;
  const float* A; const float* W; const float* bias; float* F; int rowBase;
  if (z < nb0) {
    A = o0; W = Wo_l; bias = bo_l; F = f0; rowBase = z * 128;
  } else {
    z -= nb0;
    A = o1; W = Wo_l + CC * HD_; bias = bo_l + CC; F = f1; rowBase = z * 128;
  }
  GEMM_BODY(A, rowBase, W)
  #pragma unroll
  for (int i = 0; i < 8; ++i) {
    int r = rowBase + ((i < 4) ? (ty * 4 + i) : (64 + ty * 4 + i - 4));
    float* op = F + (size_t)r * 128;
    #pragma unroll
    for (int half = 0; half < 2; ++half) {
      int c = half * 64 + tx * 4;
      float4 f = *(float4*)(op + c);
      f.x += acc[i][half * 4 + 0] + bias[c + 0];
      f.y += acc[i][half * 4 + 1] + bias[c + 1];
      f.z += acc[i][half * 4 + 2] + bias[c + 2];
      f.w += acc[i][half * 4 + 3] + bias[c + 3];
      *(float4*)(op + c) = f;
    }
  }
}

// ---------------------------------------------------------------- attn (gather + softmax + o)
__global__ __launch_bounds__(128) void k_attn(
    const float* __restrict__ P0, const float* __restrict__ P1,
    const int* __restrict__ idx, const float* __restrict__ rhat,
    const float* __restrict__ rl,
    const float* __restrict__ Wr1, const float* __restrict__ br1,
    const float* __restrict__ Wr2, const float* __restrict__ br2,
    float* __restrict__ o0buf, float* __restrict__ o1buf,
    int nodeBase, int layer)
{
  const int t = threadIdx.x;
  const int h = t >> 4;
  const int node = nodeBase + blockIdx.x;

  __shared__ float rn_s[KNN][80];
  __shared__ float hid_s[KNN][RH];
  __shared__ float rh_s[KNN][3];
  __shared__ float rl_s[KNN];

  if (t < KNN * 3) rh_s[t / 3][t % 3] = rhat[(size_t)node * KNN * 3 + t];
  if (t >= 32 && t < 32 + KNN) rl_s[t - 32] = rl[(size_t)node * KNN + (t - 32)];
  __syncthreads();

  const float* wr1 = Wr1 + layer * RH;
  const float* wb1 = br1 + layer * RH;
  #pragma unroll
  for (int u = 0; u < 2; ++u) {
    int f = u * 128 + t;
    int k = f >> 5, i = f & 31;
    float z = rl_s[k] * wr1[i] + wb1[i];
    hid_s[k][i] = z / (1.0f + expf(-z));
  }
  __syncthreads();
  const float* wr2 = Wr2 + layer * RH * 80;
  const float* wb2 = br2 + layer * 80;
  #pragma unroll
  for (int u = 0; u < 5; ++u) {
    int f = u * 128 + t;
    int k = f / 80, col = f - k * 80;
    float acc = wb2[col];
    #pragma unroll
    for (int i = 0; i < RH; ++i) acc += hid_s[k][i] * wr2[i * 80 + col];
    rn_s[k][col] = acc;
  }
  __syncthreads();

  const float* p0n = P0 + (size_t)blockIdx.x * 640;
  const size_t p1row = (size_t)blockIdx.x * 3 * 896;
  float q0  = p0n[t];
  float q1x = P1[p1row + t];
  float q1y = P1[p1row + 896 + t];
  float q1z = P1[p1row + 1792 + t];

  float logit[KNN];
  float v0k[KNN], v1xk[KNN], v1yk[KNN], v1zk[KNN];
  const float inv_scale = 0.17677669529663687f;  // 1/sqrt(32)

  #pragma unroll
  for (int k = 0; k < KNN; ++k) {
    int jj = idx[(size_t)node * KNN + k];
    int jl = ((node >> 10) << 10) + jj - nodeBase;
    const float* g0 = P0 + (size_t)jl * 640;
    const float* g1 = P1 + (size_t)jl * 3 * 896;
    float rx = rh_s[k][0], ry = rh_s[k][1], rz = rh_s[k][2];

    float G02 = g0[128 + t], G04 = g0[256 + t], G07 = g0[384 + t], G09 = g0[512 + t];
    float G13x = g1[128 + t], G13y = g1[896 + 128 + t], G13z = g1[1792 + 128 + t];
    float G15x = g1[256 + t], G15y = g1[896 + 256 + t], G15z = g1[1792 + 256 + t];
    float G16x = g1[384 + t], G16y = g1[896 + 384 + t], G16z = g1[1792 + 384 + t];
    float G18x = g1[512 + t], G18y = g1[896 + 512 + t], G18z = g1[1792 + 512 + t];
    float G1Ax = g1[640 + t], G1Ay = g1[896 + 640 + t], G1Az = g1[1792 + 640 + t];
    float G1Bx = g1[768 + t], G1By = g1[896 + 768 + t], G1Bz = g1[1792 + 768 + t];

    float DP3 = G13x * rx + G13y * ry + G13z * rz;
    float DP6 = G16x * rx + G16y * ry + G16z * rz;
    float DP8 = G18x * rx + G18y * ry + G18z * rz;
    float DPB = G1Bx * rx + G1By * ry + G1Bz * rz;

    const float* rnh = &rn_s[k][h * 10];
    float r0 = rnh[0], r1 = rnh[1], r2 = rnh[2], r3 = rnh[3], r4 = rnh[4];
    float r5 = rnh[5], r6 = rnh[6], r7 = rnh[7], r8 = rnh[8], r9 = rnh[9];

    float k0  = G02 * r0 + DP3 * r1;
    float k1x = G04 * rx * r2 + G15x * r3 + (3.0f * rx * DP6 - G16x) * r4;
    float k1y = G04 * ry * r2 + G15y * r3 + (3.0f * ry * DP6 - G16y) * r4;
    float k1z = G04 * rz * r2 + G15z * r3 + (3.0f * rz * DP6 - G16z) * r4;
    float v0  = G07 * r5 + DP8 * r6;
    float v1x = G09 * rx * r7 + G1Ax * r8 + (3.0f * rx * DPB - G1Bx) * r9;
    float v1y = G09 * ry * r7 + G1Ay * r8 + (3.0f * ry * DPB - G1By) * r9;
    float v1z = G09 * rz * r7 + G1Az * r8 + (3.0f * rz * DPB - G1Bz) * r9;

    float pl = q0 * k0 + q1x * k1x + q1y * k1y + q1z * k1z;
    pl += __shfl_xor(pl, 1, 16);
    pl += __shfl_xor(pl, 2, 16);
    pl += __shfl_xor(pl, 4, 16);
    pl += __shfl_xor(pl, 8, 16);
    logit[k] = pl * inv_scale;
    v0k[k] = v0; v1xk[k] = v1x; v1yk[k] = v1y; v1zk[k] = v1z;
  }

  float mx = logit[0];
  #pragma unroll
  for (int k = 1; k < KNN; ++k) mx = fmaxf(mx, logit[k]);
  float ssum = 0.0f;
  float wgt[KNN];
  #pragma unroll
  for (int k = 0; k < KNN; ++k) { wgt[k] = expf(logit[k] - mx); ssum += wgt[k]; }
  float invs = 1.0f / ssum;
  float o0 = 0.0f, o1x = 0.0f, o1y = 0.0f, o1z = 0.0f;
  #pragma unroll
  for (int k = 0; k < KNN; ++k) {
    float a = wgt[k] * invs;
    o0 += a * v0k[k]; o1x += a * v1xk[k]; o1y += a * v1yk[k]; o1z += a * v1zk[k];
  }
  o0buf[(size_t)blockIdx.x * CC + t] = o0;
  o1buf[((size_t)blockIdx.x * 3 + 0) * CC + t] = o1x;
  o1buf[((size_t)blockIdx.x * 3 + 1) * CC + t] = o1y;
  o1buf[((size_t)blockIdx.x * 3 + 2) * CC + t] = o1z;
}

// ---------------------------------------------------------------- final out
__global__ __launch_bounds__(256) void k_out(
    const float* __restrict__ f1, const float* __restrict__ Wout,
    const float* __restrict__ bout, float* __restrict__ out)
{
  int i = blockIdx.x * 256 + threadIdx.x;  // < 24576 rows = node*3+v
  int v = i % 3;
  const float* row = f1 + (size_t)i * CC;
  const float* w = Wout + v * CC;
  float acc = 0.0f;
  #pragma unroll
  for (int c = 0; c < CC; c += 4) {
    float4 fv = *(const float4*)&row[c];
    float4 wv = *(const float4*)&w[c];
    acc += fv.x * wv.x + fv.y * wv.y + fv.z * wv.z + fv.w * wv.w;
  }
  out[i] = acc + bout[v];
}

// ---------------------------------------------------------------- host
extern "C" void kernel_launch(void* const* d_in, const int* in_sizes, int n_in,
                              void* d_out, int out_size, void* d_ws, size_t ws_size,
                              hipStream_t stream) {
  const float* x    = (const float*)d_in[0];
  const float* t    = (const float*)d_in[2];
  const float* Wt1  = (const float*)d_in[3];
  const float* bt1  = (const float*)d_in[4];
  const float* Wt2  = (const float*)d_in[5];
  const float* bt2  = (const float*)d_in[6];
  const float* Win0 = (const float*)d_in[7];
  const float* bin0 = (const float*)d_in[8];
  const float* Win1 = (const float*)d_in[9];
  const float* Wqkv = (const float*)d_in[10];
  const float* Wr1  = (const float*)d_in[11];
  const float* br1  = (const float*)d_in[12];
  const float* Wr2  = (const float*)d_in[13];
  const float* br2  = (const float*)d_in[14];
  const float* Wo   = (const float*)d_in[15];
  const float* bo   = (const float*)d_in[16];
  const float* Wout = (const float*)d_in[17];
  const float* bout = (const float*)d_in[18];
  float* out = (float*)d_out;

  char* wsb = (char*)d_ws;
  size_t off = 0;
  auto alloc = [&](size_t bytes) -> void* {
    void* p = wsb + off;
    off = (off + bytes + 255) & ~(size_t)255;
    return p;
  };
  const int totalNodes = NBATCH * NPTS;  // 8192
  float* pre0 = (float*)alloc((size_t)NBATCH * CC * 4);
  float* f0   = (float*)alloc((size_t)totalNodes * CC * 4);
  float* f1   = (float*)alloc((size_t)totalNodes * 3 * CC * 4);
  int*   idx  = (int*)alloc((size_t)totalNodes * KNN * 4);
  float* rhat = (float*)alloc((size_t)totalNodes * KNN * 3 * 4);
  float* rl   = (float*)alloc((size_t)totalNodes * KNN * 4);
  size_t fixedBytes = off;
  size_t perBatch = (size_t)NPTS * (640 + 2688 + 128 + 384) * 4;
  int nbg = 8;
  while (nbg > 1 && fixedBytes + (size_t)nbg * perBatch + 8192 > ws_size) nbg >>= 1;
  float* P0  = (float*)alloc((size_t)nbg * NPTS * 640 * 4);
  float* P1  = (float*)alloc((size_t)nbg * NPTS * 2688 * 4);
  float* o0b = (float*)alloc((size_t)nbg * NPTS * 128 * 4);
  float* o1b = (float*)alloc((size_t)nbg * NPTS * 384 * 4);

  k_temb<<<NBATCH, 128, 0, stream>>>(t, Wt1, bt1, Wt2, bt2, Win0, bin0, pre0);
  k_init<<<totalNodes / 2, 256, 0, stream>>>(x, Win0, Win1, pre0, f0, f1);
  k_knn<<<NBATCH * 32, 256, 0, stream>>>(x, idx, rhat, rl);

  for (int g = 0; g < NBATCH / nbg; ++g) {
    int nodeBase = g * nbg * NPTS;
    int nodes = nbg * NPTS;
    int nb0 = nodes / 128;
    for (int l = 0; l < NL; ++l) {
      const float* Wl = Wqkv + (size_t)l * 12 * CC * HD_;
      k_proj_all<<<nb0 * 26, 256, 0, stream>>>(
          f0 + (size_t)nodeBase * CC, f1 + (size_t)nodeBase * 3 * CC,
          Wl, P0, P1, nb0);
      k_attn<<<nodes, 128, 0, stream>>>(
          P0, P1, idx, rhat, rl, Wr1, br1, Wr2, br2, o0b, o1b, nodeBase, l);
      k_wo<<<nb0 * 4, 256, 0, stream>>>(
          o0b, o1b, Wo + (size_t)(l * 2) * HD_ * CC, bo + (size_t)(l * 2) * CC,
          f0 + (size_t)nodeBase * CC, f1 + (size_t)nodeBase * 3 * CC, nb0);
    }
  }
  k_out<<<(totalNodes * 3) / 256, 256, 0, stream>>>(f1, Wout, bout, out);
}

// Round 4
// 803.811 us; speedup vs baseline: 1.4994x; 1.3887x over previous
//
#include <hip/hip_runtime.h>
#include <hip/hip_fp16.h>
#include <math.h>

#define NBATCH 8
#define NPTS   1024
#define KNN    8
#define CC     128
#define HD_    128
#define TED_   128
#define TEC_   64
#define RH     32
#define NL     4

__device__ __forceinline__ unsigned int pack2h(float a, float b) {
  __half2 h = __floats2half2_rn(a, b);
  return *(unsigned int*)&h;
}
__device__ __forceinline__ float h2f(__half h) { return __half2float(h); }

// ---------------------------------------------------------------- temb
__global__ __launch_bounds__(128) void k_temb(
    const float* __restrict__ t, const float* __restrict__ Wt1,
    const float* __restrict__ bt1, const float* __restrict__ Wt2,
    const float* __restrict__ bt2, const float* __restrict__ Win0,
    const float* __restrict__ bin0, float* __restrict__ pre0)
{
  int b = blockIdx.x;
  int tid = threadIdx.x;
  __shared__ float e128[TED_];
  __shared__ float h1[TED_];
  __shared__ float te[TEC_];
  float tv = t[b];
  if (tid < 64) {
    float fr = expf((-9.210340371976184f * (float)tid) * 0.015625f);
    float em = tv * fr;
    e128[tid]      = sinf(em);
    e128[tid + 64] = cosf(em);
  }
  __syncthreads();
  {
    float acc = bt1[tid];
    for (int i = 0; i < TED_; ++i) acc += e128[i] * Wt1[i * TED_ + tid];
    h1[tid] = acc / (1.0f + expf(-acc));
  }
  __syncthreads();
  if (tid < TEC_) {
    float acc = bt2[tid];
    for (int j = 0; j < TED_; ++j) acc += h1[j] * Wt2[j * TEC_ + tid];
    te[tid] = acc;
  }
  __syncthreads();
  {
    float acc = bin0[tid];
    for (int i = 0; i < TEC_; ++i) acc += te[i] * Win0[i * CC + tid];
    pre0[b * CC + tid] = acc;
  }
}

// ---------------------------------------------------------------- init f0/f1
__global__ __launch_bounds__(256) void k_init(
    const float* __restrict__ x, const float* __restrict__ Win0,
    const float* __restrict__ Win1, const float* __restrict__ pre0,
    float* __restrict__ f0, float* __restrict__ f1)
{
  int node = blockIdx.x * 2 + (threadIdx.x >> 7);
  int c = threadIdx.x & 127;
  int b = node >> 10;
  float x0 = x[node * 3 + 0], x1 = x[node * 3 + 1], x2 = x[node * 3 + 2];
  float acc = pre0[b * CC + c]
            + x0 * Win0[(TEC_ + 0) * CC + c]
            + x1 * Win0[(TEC_ + 1) * CC + c]
            + x2 * Win0[(TEC_ + 2) * CC + c];
  f0[(size_t)node * CC + c] = acc;
  float w1 = Win1[c];
  f1[((size_t)node * 3 + 0) * CC + c] = x0 * w1;
  f1[((size_t)node * 3 + 1) * CC + c] = x1 * w1;
  f1[((size_t)node * 3 + 2) * CC + c] = x2 * w1;
}

// ---------------------------------------------------------------- knn
__global__ __launch_bounds__(256) void k_knn(
    const float* __restrict__ x, int* __restrict__ idx,
    float* __restrict__ rhat, float* __restrict__ rl)
{
  const int b    = blockIdx.x >> 5;
  const int tile = blockIdx.x & 31;
  const int tid  = threadIdx.x;
  const int qg   = tid >> 3;
  const int sub  = tid & 7;

  __shared__ float xs[NPTS * 3];
  __shared__ unsigned long long keys[32][64];

  for (int i = tid; i < NPTS * 3; i += 256) xs[i] = x[(size_t)b * NPTS * 3 + i];
  __syncthreads();

  const int n = tile * 32 + qg;
  const float qx = xs[n * 3 + 0], qy = xs[n * 3 + 1], qz = xs[n * 3 + 2];

  unsigned long long bd[KNN];
  #pragma unroll
  for (int k = 0; k < KNN; ++k) bd[k] = ~0ull;

  const int j0 = sub * 128;
  for (int j = j0; j < j0 + 128; ++j) {
    float dx = qx - xs[j * 3 + 0];
    float dy = qy - xs[j * 3 + 1];
    float dz = qz - xs[j * 3 + 2];
    float s = __fadd_rn(__fadd_rn(__fmul_rn(dx, dx), __fmul_rn(dy, dy)),
                        __fmul_rn(dz, dz));
    if (j == n) s = 1.0e9f;
    unsigned long long key =
        ((unsigned long long)__float_as_uint(s) << 32) | (unsigned int)j;
    if (key < bd[KNN - 1]) {
      bd[KNN - 1] = key;
      #pragma unroll
      for (int q = KNN - 1; q > 0; --q) {
        if (bd[q] < bd[q - 1]) {
          unsigned long long tmp = bd[q]; bd[q] = bd[q - 1]; bd[q - 1] = tmp;
        }
      }
    }
  }
  #pragma unroll
  for (int k = 0; k < KNN; ++k) keys[qg][sub * KNN + k] = bd[k];
  __syncthreads();

  if (sub == 0) {
    unsigned long long m[KNN];
    #pragma unroll
    for (int k = 0; k < KNN; ++k) m[k] = ~0ull;
    for (int i = 0; i < 64; ++i) {
      unsigned long long key = keys[qg][i];
      if (key < m[KNN - 1]) {
        m[KNN - 1] = key;
        #pragma unroll
        for (int q = KNN - 1; q > 0; --q) {
          if (m[q] < m[q - 1]) {
            unsigned long long tmp = m[q]; m[q] = m[q - 1]; m[q - 1] = tmp;
          }
        }
      }
    }
    size_t base = ((size_t)b * NPTS + n) * KNN;
    #pragma unroll
    for (int k = 0; k < KNN; ++k) {
      int j = (int)(m[k] & 0xffffffffu);
      idx[base + k] = j;
      float rx = xs[j * 3 + 0] - qx;
      float ry = xs[j * 3 + 1] - qy;
      float rz = xs[j * 3 + 2] - qz;
      float rr2 = rx * rx + ry * ry + rz * rz + 1e-8f;
      float r = sqrtf(rr2);
      rl[base + k] = r;
      rhat[(base + k) * 3 + 0] = rx / r;
      rhat[(base + k) * 3 + 1] = ry / r;
      rhat[(base + k) * 3 + 2] = rz / r;
    }
  }
}

// ---------------------------------------------------------------- 128x128x128 fp32 GEMM body
// As stride 132: store 2-way aliased (free). Ws stride 132: conflict-free,
// 528B row = 33*16B keeps ds_read_b128 alignment.
#define GEMM_BODY(A_, ROWBASE_, W_)                                           \
  int tid = threadIdx.x;                                                      \
  int tx = tid & 15, ty = tid >> 4;                                           \
  __shared__ float As[32][132];                                               \
  __shared__ float Ws[32][132];                                               \
  float acc[8][8] = {};                                                       \
  for (int kk = 0; kk < 128; kk += 32) {                                      \
    {                                                                         \
      int row = tid >> 1;                                                     \
      int kq = (tid & 1) * 16;                                                \
      const float* ap = (A_) + (size_t)((ROWBASE_) + row) * 128 + kk + kq;    \
      _Pragma("unroll")                                                       \
      for (int q = 0; q < 4; ++q) {                                           \
        float4 v = *(const float4*)(ap + q * 4);                              \
        As[kq + q * 4 + 0][row] = v.x;                                        \
        As[kq + q * 4 + 1][row] = v.y;                                        \
        As[kq + q * 4 + 2][row] = v.z;                                        \
        As[kq + q * 4 + 3][row] = v.w;                                        \
      }                                                                       \
    }                                                                         \
    {                                                                         \
      int kr = tid >> 3;                                                      \
      int cq = (tid & 7) * 16;                                                \
      const float* wp = (W_) + (size_t)(kk + kr) * 128 + cq;                  \
      _Pragma("unroll")                                                       \
      for (int q = 0; q < 4; ++q)                                             \
        *(float4*)&Ws[kr][cq + q * 4] = *(const float4*)(wp + q * 4);         \
    }                                                                         \
    __syncthreads();                                                          \
    _Pragma("unroll 4")                                                       \
    for (int k = 0; k < 32; ++k) {                                            \
      float a[8], bb[8];                                                      \
      *(float4*)&a[0] = *(float4*)&As[k][ty * 4];                             \
      *(float4*)&a[4] = *(float4*)&As[k][64 + ty * 4];                        \
      *(float4*)&bb[0] = *(float4*)&Ws[k][tx * 4];                            \
      *(float4*)&bb[4] = *(float4*)&Ws[k][64 + tx * 4];                       \
      _Pragma("unroll")                                                       \
      for (int i = 0; i < 8; ++i) {                                           \
        _Pragma("unroll")                                                     \
        for (int j = 0; j < 8; ++j) acc[i][j] += a[i] * bb[j];                \
      }                                                                       \
    }                                                                         \
    __syncthreads();                                                          \
  }

// ---------------------------------------------------------------- proj (P in fp16)
__global__ __launch_bounds__(256) void k_proj_all(
    const float* __restrict__ f0, const float* __restrict__ f1,
    const float* __restrict__ Wl, __half* __restrict__ P0,
    __half* __restrict__ P1, int nb0)
{
  int z = blockIdx.x;
  const float* A; const float* W; __half* P; int ldP, colBase, rowBase;
  if (z < nb0 * 5) {
    const int map0[5] = {0, 2, 4, 7, 9};
    int m = z / nb0, rb = z - m * nb0;
    A = f0; rowBase = rb * 128;
    W = Wl + (size_t)map0[m] * (CC * HD_);
    P = P0; ldP = 640; colBase = m * 128;
  } else {
    z -= nb0 * 5;
    int nb1 = nb0 * 3;
    const int map1[7] = {1, 3, 5, 6, 8, 10, 11};
    int m = z / nb1, rb = z - m * nb1;
    A = f1; rowBase = rb * 128;
    W = Wl + (size_t)map1[m] * (CC * HD_);
    P = P1; ldP = 896; colBase = m * 128;
  }
  GEMM_BODY(A, rowBase, W)
  #pragma unroll
  for (int i = 0; i < 8; ++i) {
    int r = rowBase + ((i < 4) ? (ty * 4 + i) : (64 + ty * 4 + i - 4));
    __half* op = P + (size_t)r * ldP + colBase;
    uint2 w0, w1;
    w0.x = pack2h(acc[i][0], acc[i][1]);
    w0.y = pack2h(acc[i][2], acc[i][3]);
    w1.x = pack2h(acc[i][4], acc[i][5]);
    w1.y = pack2h(acc[i][6], acc[i][7]);
    *(uint2*)(op + tx * 4) = w0;
    *(uint2*)(op + 64 + tx * 4) = w1;
  }
}

// ---------------------------------------------------------------- Wo GEMM with residual+bias
__global__ __launch_bounds__(256) void k_wo(
    const float* __restrict__ o0, const float* __restrict__ o1,
    const float* __restrict__ Wo_l, const float* __restrict__ bo_l,
    float* __restrict__ f0, float* __restrict__ f1, int nb0)
{
  int z = blockIdx.x;
  const float* A; const float* W; const float* bias; float* F; int rowBase;
  if (z < nb0) {
    A = o0; W = Wo_l; bias = bo_l; F = f0; rowBase = z * 128;
  } else {
    z -= nb0;
    A = o1; W = Wo_l + CC * HD_; bias = bo_l + CC; F = f1; rowBase = z * 128;
  }
  GEMM_BODY(A, rowBase, W)
  #pragma unroll
  for (int i = 0; i < 8; ++i) {
    int r = rowBase + ((i < 4) ? (ty * 4 + i) : (64 + ty * 4 + i - 4));
    float* op = F + (size_t)r * 128;
    #pragma unroll
    for (int half = 0; half < 2; ++half) {
      int c = half * 64 + tx * 4;
      float4 f = *(float4*)(op + c);
      f.x += acc[i][half * 4 + 0] + bias[c + 0];
      f.y += acc[i][half * 4 + 1] + bias[c + 1];
      f.z += acc[i][half * 4 + 2] + bias[c + 2];
      f.w += acc[i][half * 4 + 3] + bias[c + 3];
      *(float4*)(op + c) = f;
    }
  }
}

// ---------------------------------------------------------------- attn (fp16 gather)
__global__ __launch_bounds__(128) void k_attn(
    const __half* __restrict__ P0, const __half* __restrict__ P1,
    const int* __restrict__ idx, const float* __restrict__ rhat,
    const float* __restrict__ rl,
    const float* __restrict__ Wr1, const float* __restrict__ br1,
    const float* __restrict__ Wr2, const float* __restrict__ br2,
    float* __restrict__ o0buf, float* __restrict__ o1buf,
    int nodeBase, int layer, int nbg)
{
  const int t = threadIdx.x;
  const int h = t >> 4;
  // XCD-affinity remap: batch-in-group = z % nbg -> pins one batch per XCD
  const int z = blockIdx.x;
  const int nodeLocal = (z % nbg) * NPTS + (z / nbg);
  const int node = nodeBase + nodeLocal;
  const int batchRow = (nodeLocal >> 10) << 10;

  __shared__ float rn_s[KNN][80];
  __shared__ float hid_s[KNN][RH];
  __shared__ float rh_s[KNN][3];
  __shared__ float rl_s[KNN];

  if (t < KNN * 3) rh_s[t / 3][t % 3] = rhat[(size_t)node * KNN * 3 + t];
  if (t >= 32 && t < 32 + KNN) rl_s[t - 32] = rl[(size_t)node * KNN + (t - 32)];
  __syncthreads();

  const float* wr1 = Wr1 + layer * RH;
  const float* wb1 = br1 + layer * RH;
  #pragma unroll
  for (int u = 0; u < 2; ++u) {
    int f = u * 128 + t;
    int k = f >> 5, i = f & 31;
    float zv = rl_s[k] * wr1[i] + wb1[i];
    hid_s[k][i] = zv / (1.0f + expf(-zv));
  }
  __syncthreads();
  const float* wr2 = Wr2 + layer * RH * 80;
  const float* wb2 = br2 + layer * 80;
  #pragma unroll
  for (int u = 0; u < 5; ++u) {
    int f = u * 128 + t;
    int k = f / 80, col = f - k * 80;
    float acc = wb2[col];
    #pragma unroll
    for (int i = 0; i < RH; ++i) acc += hid_s[k][i] * wr2[i * 80 + col];
    rn_s[k][col] = acc;
  }
  __syncthreads();

  const __half* p0n = P0 + (size_t)nodeLocal * 640;
  const size_t p1row = (size_t)nodeLocal * 3 * 896;
  float q0  = h2f(p0n[t]);
  float q1x = h2f(P1[p1row + t]);
  float q1y = h2f(P1[p1row + 896 + t]);
  float q1z = h2f(P1[p1row + 1792 + t]);

  float logit[KNN];
  float v0k[KNN], v1xk[KNN], v1yk[KNN], v1zk[KNN];
  const float inv_scale = 0.17677669529663687f;  // 1/sqrt(32)

  #pragma unroll
  for (int k = 0; k < KNN; ++k) {
    int jj = idx[(size_t)node * KNN + k];
    int jl = batchRow + jj;
    const __half* g0 = P0 + (size_t)jl * 640;
    const __half* g1 = P1 + (size_t)jl * 3 * 896;
    float rx = rh_s[k][0], ry = rh_s[k][1], rz = rh_s[k][2];

    float G02 = h2f(g0[128 + t]), G04 = h2f(g0[256 + t]);
    float G07 = h2f(g0[384 + t]), G09 = h2f(g0[512 + t]);
    float G13x = h2f(g1[128 + t]), G13y = h2f(g1[896 + 128 + t]), G13z = h2f(g1[1792 + 128 + t]);
    float G15x = h2f(g1[256 + t]), G15y = h2f(g1[896 + 256 + t]), G15z = h2f(g1[1792 + 256 + t]);
    float G16x = h2f(g1[384 + t]), G16y = h2f(g1[896 + 384 + t]), G16z = h2f(g1[1792 + 384 + t]);
    float G18x = h2f(g1[512 + t]), G18y = h2f(g1[896 + 512 + t]), G18z = h2f(g1[1792 + 512 + t]);
    float G1Ax = h2f(g1[640 + t]), G1Ay = h2f(g1[896 + 640 + t]), G1Az = h2f(g1[1792 + 640 + t]);
    float G1Bx = h2f(g1[768 + t]), G1By = h2f(g1[896 + 768 + t]), G1Bz = h2f(g1[1792 + 768 + t]);

    float DP3 = G13x * rx + G13y * ry + G13z * rz;
    float DP6 = G16x * rx + G16y * ry + G16z * rz;
    float DP8 = G18x * rx + G18y * ry + G18z * rz;
    float DPB = G1Bx * rx + G1By * ry + G1Bz * rz;

    const float* rnh = &rn_s[k][h * 10];
    float r0 = rnh[0], r1 = rnh[1], r2 = rnh[2], r3 = rnh[3], r4 = rnh[4];
    float r5 = rnh[5], r6 = rnh[6], r7 = rnh[7], r8 = rnh[8], r9 = rnh[9];

    float k0  = G02 * r0 + DP3 * r1;
    float k1x = G04 * rx * r2 + G15x * r3 + (3.0f * rx * DP6 - G16x) * r4;
    float k1y = G04 * ry * r2 + G15y * r3 + (3.0f * ry * DP6 - G16y) * r4;
    float k1z = G04 * rz * r2 + G15z * r3 + (3.0f * rz * DP6 - G16z) * r4;
    float v0  = G07 * r5 + DP8 * r6;
    float v1x = G09 * rx * r7 + G1Ax * r8 + (3.0f * rx * DPB - G1Bx) * r9;
    float v1y = G09 * ry * r7 + G1Ay * r8 + (3.0f * ry * DPB - G1By) * r9;
    float v1z = G09 * rz * r7 + G1Az * r8 + (3.0f * rz * DPB - G1Bz) * r9;

    float pl = q0 * k0 + q1x * k1x + q1y * k1y + q1z * k1z;
    pl += __shfl_xor(pl, 1, 16);
    pl += __shfl_xor(pl, 2, 16);
    pl += __shfl_xor(pl, 4, 16);
    pl += __shfl_xor(pl, 8, 16);
    logit[k] = pl * inv_scale;
    v0k[k] = v0; v1xk[k] = v1x; v1yk[k] = v1y; v1zk[k] = v1z;
  }

  float mx = logit[0];
  #pragma unroll
  for (int k = 1; k < KNN; ++k) mx = fmaxf(mx, logit[k]);
  float ssum = 0.0f;
  float wgt[KNN];
  #pragma unroll
  for (int k = 0; k < KNN; ++k) { wgt[k] = expf(logit[k] - mx); ssum += wgt[k]; }
  float invs = 1.0f / ssum;
  float o0 = 0.0f, o1x = 0.0f, o1y = 0.0f, o1z = 0.0f;
  #pragma unroll
  for (int k = 0; k < KNN; ++k) {
    float a = wgt[k] * invs;
    o0 += a * v0k[k]; o1x += a * v1xk[k]; o1y += a * v1yk[k]; o1z += a * v1zk[k];
  }
  o0buf[(size_t)nodeLocal * CC + t] = o0;
  o1buf[((size_t)nodeLocal * 3 + 0) * CC + t] = o1x;
  o1buf[((size_t)nodeLocal * 3 + 1) * CC + t] = o1y;
  o1buf[((size_t)nodeLocal * 3 + 2) * CC + t] = o1z;
}

// ---------------------------------------------------------------- final out
__global__ __launch_bounds__(256) void k_out(
    const float* __restrict__ f1, const float* __restrict__ Wout,
    const float* __restrict__ bout, float* __restrict__ out)
{
  int i = blockIdx.x * 256 + threadIdx.x;
  int v = i % 3;
  const float* row = f1 + (size_t)i * CC;
  const float* w = Wout + v * CC;
  float acc = 0.0f;
  #pragma unroll
  for (int c = 0; c < CC; c += 4) {
    float4 fv = *(const float4*)&row[c];
    float4 wv = *(const float4*)&w[c];
    acc += fv.x * wv.x + fv.y * wv.y + fv.z * wv.z + fv.w * wv.w;
  }
  out[i] = acc + bout[v];
}

// ---------------------------------------------------------------- host
extern "C" void kernel_launch(void* const* d_in, const int* in_sizes, int n_in,
                              void* d_out, int out_size, void* d_ws, size_t ws_size,
                              hipStream_t stream) {
  const float* x    = (const float*)d_in[0];
  const float* t    = (const float*)d_in[2];
  const float* Wt1  = (const float*)d_in[3];
  const float* bt1  = (const float*)d_in[4];
  const float* Wt2  = (const float*)d_in[5];
  const float* bt2  = (const float*)d_in[6];
  const float* Win0 = (const float*)d_in[7];
  const float* bin0 = (const float*)d_in[8];
  const float* Win1 = (const float*)d_in[9];
  const float* Wqkv = (const float*)d_in[10];
  const float* Wr1  = (const float*)d_in[11];
  const float* br1  = (const float*)d_in[12];
  const float* Wr2  = (const float*)d_in[13];
  const float* br2  = (const float*)d_in[14];
  const float* Wo   = (const float*)d_in[15];
  const float* bo   = (const float*)d_in[16];
  const float* Wout = (const float*)d_in[17];
  const float* bout = (const float*)d_in[18];
  float* out = (float*)d_out;

  char* wsb = (char*)d_ws;
  size_t off = 0;
  auto alloc = [&](size_t bytes) -> void* {
    void* p = wsb + off;
    off = (off + bytes + 255) & ~(size_t)255;
    return p;
  };
  const int totalNodes = NBATCH * NPTS;  // 8192
  float* pre0 = (float*)alloc((size_t)NBATCH * CC * 4);
  float* f0   = (float*)alloc((size_t)totalNodes * CC * 4);
  float* f1   = (float*)alloc((size_t)totalNodes * 3 * CC * 4);
  int*   idx  = (int*)alloc((size_t)totalNodes * KNN * 4);
  float* rhat = (float*)alloc((size_t)totalNodes * KNN * 3 * 4);
  float* rl   = (float*)alloc((size_t)totalNodes * KNN * 4);
  size_t fixedBytes = off;
  // per batch: P0 640*2B + P1 2688*2B + o0 128*4B + o1 384*4B per node
  size_t perBatch = (size_t)NPTS * ((640 + 2688) * 2 + (128 + 384) * 4);
  int nbg = 8;
  while (nbg > 1 && fixedBytes + (size_t)nbg * perBatch + 8192 > ws_size) nbg >>= 1;
  __half* P0 = (__half*)alloc((size_t)nbg * NPTS * 640 * 2);
  __half* P1 = (__half*)alloc((size_t)nbg * NPTS * 2688 * 2);
  float* o0b = (float*)alloc((size_t)nbg * NPTS * 128 * 4);
  float* o1b = (float*)alloc((size_t)nbg * NPTS * 384 * 4);

  k_temb<<<NBATCH, 128, 0, stream>>>(t, Wt1, bt1, Wt2, bt2, Win0, bin0, pre0);
  k_init<<<totalNodes / 2, 256, 0, stream>>>(x, Win0, Win1, pre0, f0, f1);
  k_knn<<<NBATCH * 32, 256, 0, stream>>>(x, idx, rhat, rl);

  for (int g = 0; g < NBATCH / nbg; ++g) {
    int nodeBase = g * nbg * NPTS;
    int nodes = nbg * NPTS;
    int nb0 = nodes / 128;
    for (int l = 0; l < NL; ++l) {
      const float* Wl = Wqkv + (size_t)l * 12 * CC * HD_;
      k_proj_all<<<nb0 * 26, 256, 0, stream>>>(
          f0 + (size_t)nodeBase * CC, f1 + (size_t)nodeBase * 3 * CC,
          Wl, P0, P1, nb0);
      k_attn<<<nodes, 128, 0, stream>>>(
          P0, P1, idx, rhat, rl, Wr1, br1, Wr2, br2, o0b, o1b, nodeBase, l, nbg);
      k_wo<<<nb0 * 4, 256, 0, stream>>>(
          o0b, o1b, Wo + (size_t)(l * 2) * HD_ * CC, bo + (size_t)(l * 2) * CC,
          f0 + (size_t)nodeBase * CC, f1 + (size_t)nodeBase * 3 * CC, nb0);
    }
  }
  k_out<<<(totalNodes * 3) / 256, 256, 0, stream>>>(f1, Wout, bout, out);
}

// Round 5
// 550.743 us; speedup vs baseline: 2.1883x; 1.4595x over previous
//
#include <hip/hip_runtime.h>
#include <math.h>

#define NBATCH 8
#define NPTS   1024
#define KNN    8
#define CC     128
#define HD_    128
#define TED_   128
#define TEC_   64
#define RH     32
#define NL     4

typedef _Float16 half8 __attribute__((ext_vector_type(8)));
typedef float f32x4 __attribute__((ext_vector_type(4)));

// ---------------------------------------------------------------- temb
__global__ __launch_bounds__(128) void k_temb(
    const float* __restrict__ t, const float* __restrict__ Wt1,
    const float* __restrict__ bt1, const float* __restrict__ Wt2,
    const float* __restrict__ bt2, const float* __restrict__ Win0,
    const float* __restrict__ bin0, float* __restrict__ pre0)
{
  int b = blockIdx.x;
  int tid = threadIdx.x;
  __shared__ float e128[TED_];
  __shared__ float h1[TED_];
  __shared__ float te[TEC_];
  float tv = t[b];
  if (tid < 64) {
    float fr = expf((-9.210340371976184f * (float)tid) * 0.015625f);
    float em = tv * fr;
    e128[tid]      = sinf(em);
    e128[tid + 64] = cosf(em);
  }
  __syncthreads();
  {
    float acc = bt1[tid];
    for (int i = 0; i < TED_; ++i) acc += e128[i] * Wt1[i * TED_ + tid];
    h1[tid] = acc / (1.0f + expf(-acc));
  }
  __syncthreads();
  if (tid < TEC_) {
    float acc = bt2[tid];
    for (int j = 0; j < TED_; ++j) acc += h1[j] * Wt2[j * TEC_ + tid];
    te[tid] = acc;
  }
  __syncthreads();
  {
    float acc = bin0[tid];
    for (int i = 0; i < TEC_; ++i) acc += te[i] * Win0[i * CC + tid];
    pre0[b * CC + tid] = acc;
  }
}

// ---------------------------------------------------------------- init f0/f1 (+fp16 copies)
__global__ __launch_bounds__(256) void k_init(
    const float* __restrict__ x, const float* __restrict__ Win0,
    const float* __restrict__ Win1, const float* __restrict__ pre0,
    float* __restrict__ f0, float* __restrict__ f1,
    _Float16* __restrict__ f0h, _Float16* __restrict__ f1h)
{
  int node = blockIdx.x * 2 + (threadIdx.x >> 7);
  int c = threadIdx.x & 127;
  int b = node >> 10;
  float x0 = x[node * 3 + 0], x1 = x[node * 3 + 1], x2 = x[node * 3 + 2];
  float acc = pre0[b * CC + c]
            + x0 * Win0[(TEC_ + 0) * CC + c]
            + x1 * Win0[(TEC_ + 1) * CC + c]
            + x2 * Win0[(TEC_ + 2) * CC + c];
  f0[(size_t)node * CC + c] = acc;
  f0h[(size_t)node * CC + c] = (_Float16)acc;
  float w1 = Win1[c];
  float v0 = x0 * w1, v1 = x1 * w1, v2 = x2 * w1;
  f1[((size_t)node * 3 + 0) * CC + c] = v0;
  f1[((size_t)node * 3 + 1) * CC + c] = v1;
  f1[((size_t)node * 3 + 2) * CC + c] = v2;
  f1h[((size_t)node * 3 + 0) * CC + c] = (_Float16)v0;
  f1h[((size_t)node * 3 + 1) * CC + c] = (_Float16)v1;
  f1h[((size_t)node * 3 + 2) * CC + c] = (_Float16)v2;
}

// ---------------------------------------------------------------- knn
__global__ __launch_bounds__(256) void k_knn(
    const float* __restrict__ x, int* __restrict__ idx,
    float* __restrict__ rhat, float* __restrict__ rl)
{
  const int b    = blockIdx.x >> 5;
  const int tile = blockIdx.x & 31;
  const int tid  = threadIdx.x;
  const int qg   = tid >> 3;
  const int sub  = tid & 7;

  __shared__ float xs[NPTS * 3];
  __shared__ unsigned long long keys[32][64];

  for (int i = tid; i < NPTS * 3; i += 256) xs[i] = x[(size_t)b * NPTS * 3 + i];
  __syncthreads();

  const int n = tile * 32 + qg;
  const float qx = xs[n * 3 + 0], qy = xs[n * 3 + 1], qz = xs[n * 3 + 2];

  unsigned long long bd[KNN];
  #pragma unroll
  for (int k = 0; k < KNN; ++k) bd[k] = ~0ull;

  const int j0 = sub * 128;
  for (int j = j0; j < j0 + 128; ++j) {
    float dx = qx - xs[j * 3 + 0];
    float dy = qy - xs[j * 3 + 1];
    float dz = qz - xs[j * 3 + 2];
    float s = __fadd_rn(__fadd_rn(__fmul_rn(dx, dx), __fmul_rn(dy, dy)),
                        __fmul_rn(dz, dz));
    if (j == n) s = 1.0e9f;
    unsigned long long key =
        ((unsigned long long)__float_as_uint(s) << 32) | (unsigned int)j;
    if (key < bd[KNN - 1]) {
      bd[KNN - 1] = key;
      #pragma unroll
      for (int q = KNN - 1; q > 0; --q) {
        if (bd[q] < bd[q - 1]) {
          unsigned long long tmp = bd[q]; bd[q] = bd[q - 1]; bd[q - 1] = tmp;
        }
      }
    }
  }
  #pragma unroll
  for (int k = 0; k < KNN; ++k) keys[qg][sub * KNN + k] = bd[k];
  __syncthreads();

  if (sub == 0) {
    unsigned long long m[KNN];
    #pragma unroll
    for (int k = 0; k < KNN; ++k) m[k] = ~0ull;
    for (int i = 0; i < 64; ++i) {
      unsigned long long key = keys[qg][i];
      if (key < m[KNN - 1]) {
        m[KNN - 1] = key;
        #pragma unroll
        for (int q = KNN - 1; q > 0; --q) {
          if (m[q] < m[q - 1]) {
            unsigned long long tmp = m[q]; m[q] = m[q - 1]; m[q - 1] = tmp;
          }
        }
      }
    }
    size_t base = ((size_t)b * NPTS + n) * KNN;
    #pragma unroll
    for (int k = 0; k < KNN; ++k) {
      int j = (int)(m[k] & 0xffffffffu);
      idx[base + k] = j;
      float rx = xs[j * 3 + 0] - qx;
      float ry = xs[j * 3 + 1] - qy;
      float rz = xs[j * 3 + 2] - qz;
      float rr2 = rx * rx + ry * ry + rz * rz + 1e-8f;
      float r = sqrtf(rr2);
      rl[base + k] = r;
      rhat[(base + k) * 3 + 0] = rx / r;
      rhat[(base + k) * 3 + 1] = ry / r;
      rhat[(base + k) * 3 + 2] = rz / r;
    }
  }
}

// ---------------------------------------------------------------- W convert+transpose (once)
// Wqkv [48][128k][128n] fp32 -> Wh [48][128n][128k] fp16
__global__ __launch_bounds__(256) void k_wconv(
    const float* __restrict__ Wqkv, _Float16* __restrict__ Wh)
{
  __shared__ _Float16 T[128][136];
  const float* src = Wqkv + (size_t)blockIdx.x * 16384;
  _Float16* dst = Wh + (size_t)blockIdx.x * 16384;
  int tid = threadIdx.x;
  for (int i = tid; i < 16384; i += 256) {
    int k = i >> 7, n = i & 127;
    T[n][k] = (_Float16)src[i];
  }
  __syncthreads();
  for (int i = tid; i < 16384; i += 256) {
    int n = i >> 7, k = i & 127;
    dst[i] = T[n][k];
  }
}

// ---------------------------------------------------------------- proj MFMA
// P[row, colBase+c] = sum_k A[row,k] * Wt[c,k]   (Wt pre-transposed fp16)
// block: 128x128 tile; 4 waves, each 8 M-tiles x 2 N-tiles of 16x16x32 MFMA.
__global__ __launch_bounds__(256) void k_proj_mfma(
    const _Float16* __restrict__ f0h, const _Float16* __restrict__ f1h,
    const _Float16* __restrict__ Wh, _Float16* __restrict__ P0,
    _Float16* __restrict__ P1, int nb0)
{
  __shared__ _Float16 As[128][136];   // pad 136: 8 lanes/bank-quad on b128 reads
  int z = blockIdx.x;
  const _Float16* A; const _Float16* Wt; _Float16* P; int ldP, colBase, rowBase;
  if (z < nb0 * 5) {
    const int map0[5] = {0, 2, 4, 7, 9};
    int m = z / nb0, rb = z - m * nb0;
    A = f0h; rowBase = rb * 128;
    Wt = Wh + (size_t)map0[m] * 16384;
    P = P0; ldP = 640; colBase = m * 128;
  } else {
    z -= nb0 * 5;
    int nb1 = nb0 * 3;
    const int map1[7] = {1, 3, 5, 6, 8, 10, 11};
    int m = z / nb1, rb = z - m * nb1;
    A = f1h; rowBase = rb * 128;
    Wt = Wh + (size_t)map1[m] * 16384;
    P = P1; ldP = 896; colBase = m * 128;
  }
  const int tid  = threadIdx.x;
  const int lane = tid & 63;
  const int w    = tid >> 6;
  const int r15  = lane & 15;
  const int g    = lane >> 4;

  // preload all B fragments from global (L2-resident weights)
  half8 bf[2][4];
  #pragma unroll
  for (int ntl = 0; ntl < 2; ++ntl) {
    int n = (w * 2 + ntl) * 16 + r15;
    const _Float16* wp = Wt + (size_t)n * 128 + g * 8;
    #pragma unroll
    for (int ks = 0; ks < 4; ++ks)
      bf[ntl][ks] = *(const half8*)(wp + ks * 32);
  }
  // stage A tile into LDS
  {
    int r = tid >> 1;
    const _Float16* src = A + (size_t)(rowBase + r) * 128;
    int c0 = (tid & 1) * 8;
    #pragma unroll
    for (int q = 0; q < 8; ++q) {
      int c = c0 + q;
      *(uint4*)&As[r][c * 8] = *(const uint4*)(src + c * 8);
    }
  }
  __syncthreads();

  f32x4 acc[8][2] = {};
  #pragma unroll
  for (int ks = 0; ks < 4; ++ks) {
    half8 a[8];
    #pragma unroll
    for (int mt = 0; mt < 8; ++mt)
      a[mt] = *(const half8*)&As[mt * 16 + r15][ks * 32 + g * 8];
    #pragma unroll
    for (int mt = 0; mt < 8; ++mt) {
      acc[mt][0] = __builtin_amdgcn_mfma_f32_16x16x32_f16(a[mt], bf[0][ks], acc[mt][0], 0, 0, 0);
      acc[mt][1] = __builtin_amdgcn_mfma_f32_16x16x32_f16(a[mt], bf[1][ks], acc[mt][1], 0, 0, 0);
    }
  }
  // store: D layout col=lane&15, row=(lane>>4)*4+i (m89-verified)
  #pragma unroll
  for (int mt = 0; mt < 8; ++mt) {
    #pragma unroll
    for (int ntl = 0; ntl < 2; ++ntl) {
      int col = colBase + (w * 2 + ntl) * 16 + r15;
      #pragma unroll
      for (int i = 0; i < 4; ++i) {
        int r = rowBase + mt * 16 + g * 4 + i;
        P[(size_t)r * ldP + col] = (_Float16)acc[mt][ntl][i];
      }
    }
  }
}

// ---------------------------------------------------------------- fp32 GEMM body (k_wo)
#define GEMM_BODY(A_, ROWBASE_, W_)                                           \
  int tid = threadIdx.x;                                                      \
  int tx = tid & 15, ty = tid >> 4;                                           \
  __shared__ float As[32][132];                                               \
  __shared__ float Ws[32][132];                                               \
  float acc[8][8] = {};                                                       \
  for (int kk = 0; kk < 128; kk += 32) {                                      \
    {                                                                         \
      int row = tid >> 1;                                                     \
      int kq = (tid & 1) * 16;                                                \
      const float* ap = (A_) + (size_t)((ROWBASE_) + row) * 128 + kk + kq;    \
      _Pragma("unroll")                                                       \
      for (int q = 0; q < 4; ++q) {                                           \
        float4 v = *(const float4*)(ap + q * 4);                              \
        As[kq + q * 4 + 0][row] = v.x;                                        \
        As[kq + q * 4 + 1][row] = v.y;                                        \
        As[kq + q * 4 + 2][row] = v.z;                                        \
        As[kq + q * 4 + 3][row] = v.w;                                        \
      }                                                                       \
    }                                                                         \
    {                                                                         \
      int kr = tid >> 3;                                                      \
      int cq = (tid & 7) * 16;                                                \
      const float* wp = (W_) + (size_t)(kk + kr) * 128 + cq;                  \
      _Pragma("unroll")                                                       \
      for (int q = 0; q < 4; ++q)                                             \
        *(float4*)&Ws[kr][cq + q * 4] = *(const float4*)(wp + q * 4);         \
    }                                                                         \
    __syncthreads();                                                          \
    _Pragma("unroll 4")                                                       \
    for (int k = 0; k < 32; ++k) {                                            \
      float a[8], bb[8];                                                      \
      *(float4*)&a[0] = *(float4*)&As[k][ty * 4];                             \
      *(float4*)&a[4] = *(float4*)&As[k][64 + ty * 4];                        \
      *(float4*)&bb[0] = *(float4*)&Ws[k][tx * 4];                            \
      *(float4*)&bb[4] = *(float4*)&Ws[k][64 + tx * 4];                       \
      _Pragma("unroll")                                                       \
      for (int i = 0; i < 8; ++i) {                                           \
        _Pragma("unroll")                                                     \
        for (int j = 0; j < 8; ++j) acc[i][j] += a[i] * bb[j];                \
      }                                                                       \
    }                                                                         \
    __syncthreads();                                                          \
  }

// ---------------------------------------------------------------- Wo GEMM + residual (+fp16 copy)
__global__ __launch_bounds__(256) void k_wo(
    const float* __restrict__ o0, const float* __restrict__ o1,
    const float* __restrict__ Wo_l, const float* __restrict__ bo_l,
    float* __restrict__ f0, float* __restrict__ f1,
    _Float16* __restrict__ f0h, _Float16* __restrict__ f1h, int nb0)
{
  int z = blockIdx.x;
  const float* A; const float* W; const float* bias; float* F; _Float16* FH; int rowBase;
  if (z < nb0) {
    A = o0; W = Wo_l; bias = bo_l; F = f0; FH = f0h; rowBase = z * 128;
  } else {
    z -= nb0;
    A = o1; W = Wo_l + CC * HD_; bias = bo_l + CC; F = f1; FH = f1h; rowBase = z * 128;
  }
  GEMM_BODY(A, rowBase, W)
  #pragma unroll
  for (int i = 0; i < 8; ++i) {
    int r = rowBase + ((i < 4) ? (ty * 4 + i) : (64 + ty * 4 + i - 4));
    float* op = F + (size_t)r * 128;
    _Float16* oh = FH + (size_t)r * 128;
    #pragma unroll
    for (int half = 0; half < 2; ++half) {
      int c = half * 64 + tx * 4;
      float4 f = *(float4*)(op + c);
      f.x += acc[i][half * 4 + 0] + bias[c + 0];
      f.y += acc[i][half * 4 + 1] + bias[c + 1];
      f.z += acc[i][half * 4 + 2] + bias[c + 2];
      f.w += acc[i][half * 4 + 3] + bias[c + 3];
      *(float4*)(op + c) = f;
      oh[c + 0] = (_Float16)f.x;
      oh[c + 1] = (_Float16)f.y;
      oh[c + 2] = (_Float16)f.z;
      oh[c + 3] = (_Float16)f.w;
    }
  }
}

// ---------------------------------------------------------------- attn (fp16 gather)
__global__ __launch_bounds__(128) void k_attn(
    const _Float16* __restrict__ P0, const _Float16* __restrict__ P1,
    const int* __restrict__ idx, const float* __restrict__ rhat,
    const float* __restrict__ rl,
    const float* __restrict__ Wr1, const float* __restrict__ br1,
    const float* __restrict__ Wr2, const float* __restrict__ br2,
    float* __restrict__ o0buf, float* __restrict__ o1buf,
    int nodeBase, int layer, int nbg)
{
  const int t = threadIdx.x;
  const int h = t >> 4;
  const int z = blockIdx.x;
  const int nodeLocal = (z % nbg) * NPTS + (z / nbg);
  const int node = nodeBase + nodeLocal;
  const int batchRow = (nodeLocal >> 10) << 10;

  __shared__ float rn_s[KNN][80];
  __shared__ float hid_s[KNN][RH];
  __shared__ float rh_s[KNN][3];
  __shared__ float rl_s[KNN];

  if (t < KNN * 3) rh_s[t / 3][t % 3] = rhat[(size_t)node * KNN * 3 + t];
  if (t >= 32 && t < 32 + KNN) rl_s[t - 32] = rl[(size_t)node * KNN + (t - 32)];
  __syncthreads();

  const float* wr1 = Wr1 + layer * RH;
  const float* wb1 = br1 + layer * RH;
  #pragma unroll
  for (int u = 0; u < 2; ++u) {
    int f = u * 128 + t;
    int k = f >> 5, i = f & 31;
    float zv = rl_s[k] * wr1[i] + wb1[i];
    hid_s[k][i] = zv / (1.0f + expf(-zv));
  }
  __syncthreads();
  const float* wr2 = Wr2 + layer * RH * 80;
  const float* wb2 = br2 + layer * 80;
  #pragma unroll
  for (int u = 0; u < 5; ++u) {
    int f = u * 128 + t;
    int k = f / 80, col = f - k * 80;
    float acc = wb2[col];
    #pragma unroll
    for (int i = 0; i < RH; ++i) acc += hid_s[k][i] * wr2[i * 80 + col];
    rn_s[k][col] = acc;
  }
  __syncthreads();

  const _Float16* p0n = P0 + (size_t)nodeLocal * 640;
  const size_t p1row = (size_t)nodeLocal * 3 * 896;
  float q0  = (float)p0n[t];
  float q1x = (float)P1[p1row + t];
  float q1y = (float)P1[p1row + 896 + t];
  float q1z = (float)P1[p1row + 1792 + t];

  float logit[KNN];
  float v0k[KNN], v1xk[KNN], v1yk[KNN], v1zk[KNN];
  const float inv_scale = 0.17677669529663687f;  // 1/sqrt(32)

  #pragma unroll
  for (int k = 0; k < KNN; ++k) {
    int jj = idx[(size_t)node * KNN + k];
    int jl = batchRow + jj;
    const _Float16* g0 = P0 + (size_t)jl * 640;
    const _Float16* g1 = P1 + (size_t)jl * 3 * 896;
    float rx = rh_s[k][0], ry = rh_s[k][1], rz = rh_s[k][2];

    float G02 = (float)g0[128 + t], G04 = (float)g0[256 + t];
    float G07 = (float)g0[384 + t], G09 = (float)g0[512 + t];
    float G13x = (float)g1[128 + t], G13y = (float)g1[896 + 128 + t], G13z = (float)g1[1792 + 128 + t];
    float G15x = (float)g1[256 + t], G15y = (float)g1[896 + 256 + t], G15z = (float)g1[1792 + 256 + t];
    float G16x = (float)g1[384 + t], G16y = (float)g1[896 + 384 + t], G16z = (float)g1[1792 + 384 + t];
    float G18x = (float)g1[512 + t], G18y = (float)g1[896 + 512 + t], G18z = (float)g1[1792 + 512 + t];
    float G1Ax = (float)g1[640 + t], G1Ay = (float)g1[896 + 640 + t], G1Az = (float)g1[1792 + 640 + t];
    float G1Bx = (float)g1[768 + t], G1By = (float)g1[896 + 768 + t], G1Bz = (float)g1[1792 + 768 + t];

    float DP3 = G13x * rx + G13y * ry + G13z * rz;
    float DP6 = G16x * rx + G16y * ry + G16z * rz;
    float DP8 = G18x * rx + G18y * ry + G18z * rz;
    float DPB = G1Bx * rx + G1By * ry + G1Bz * rz;

    const float* rnh = &rn_s[k][h * 10];
    float r0 = rnh[0], r1 = rnh[1], r2 = rnh[2], r3 = rnh[3], r4 = rnh[4];
    float r5 = rnh[5], r6 = rnh[6], r7 = rnh[7], r8 = rnh[8], r9 = rnh[9];

    float k0  = G02 * r0 + DP3 * r1;
    float k1x = G04 * rx * r2 + G15x * r3 + (3.0f * rx * DP6 - G16x) * r4;
    float k1y = G04 * ry * r2 + G15y * r3 + (3.0f * ry * DP6 - G16y) * r4;
    float k1z = G04 * rz * r2 + G15z * r3 + (3.0f * rz * DP6 - G16z) * r4;
    float v0  = G07 * r5 + DP8 * r6;
    float v1x = G09 * rx * r7 + G1Ax * r8 + (3.0f * rx * DPB - G1Bx) * r9;
    float v1y = G09 * ry * r7 + G1Ay * r8 + (3.0f * ry * DPB - G1By) * r9;
    float v1z = G09 * rz * r7 + G1Az * r8 + (3.0f * rz * DPB - G1Bz) * r9;

    float pl = q0 * k0 + q1x * k1x + q1y * k1y + q1z * k1z;
    pl += __shfl_xor(pl, 1, 16);
    pl += __shfl_xor(pl, 2, 16);
    pl += __shfl_xor(pl, 4, 16);
    pl += __shfl_xor(pl, 8, 16);
    logit[k] = pl * inv_scale;
    v0k[k] = v0; v1xk[k] = v1x; v1yk[k] = v1y; v1zk[k] = v1z;
  }

  float mx = logit[0];
  #pragma unroll
  for (int k = 1; k < KNN; ++k) mx = fmaxf(mx, logit[k]);
  float ssum = 0.0f;
  float wgt[KNN];
  #pragma unroll
  for (int k = 0; k < KNN; ++k) { wgt[k] = expf(logit[k] - mx); ssum += wgt[k]; }
  float invs = 1.0f / ssum;
  float o0 = 0.0f, o1x = 0.0f, o1y = 0.0f, o1z = 0.0f;
  #pragma unroll
  for (int k = 0; k < KNN; ++k) {
    float a = wgt[k] * invs;
    o0 += a * v0k[k]; o1x += a * v1xk[k]; o1y += a * v1yk[k]; o1z += a * v1zk[k];
  }
  o0buf[(size_t)nodeLocal * CC + t] = o0;
  o1buf[((size_t)nodeLocal * 3 + 0) * CC + t] = o1x;
  o1buf[((size_t)nodeLocal * 3 + 1) * CC + t] = o1y;
  o1buf[((size_t)nodeLocal * 3 + 2) * CC + t] = o1z;
}

// ---------------------------------------------------------------- final out
__global__ __launch_bounds__(256) void k_out(
    const float* __restrict__ f1, const float* __restrict__ Wout,
    const float* __restrict__ bout, float* __restrict__ out)
{
  int i = blockIdx.x * 256 + threadIdx.x;
  int v = i % 3;
  const float* row = f1 + (size_t)i * CC;
  const float* w = Wout + v * CC;
  float acc = 0.0f;
  #pragma unroll
  for (int c = 0; c < CC; c += 4) {
    float4 fv = *(const float4*)&row[c];
    float4 wv = *(const float4*)&w[c];
    acc += fv.x * wv.x + fv.y * wv.y + fv.z * wv.z + fv.w * wv.w;
  }
  out[i] = acc + bout[v];
}

// ---------------------------------------------------------------- host
extern "C" void kernel_launch(void* const* d_in, const int* in_sizes, int n_in,
                              void* d_out, int out_size, void* d_ws, size_t ws_size,
                              hipStream_t stream) {
  const float* x    = (const float*)d_in[0];
  const float* t    = (const float*)d_in[2];
  const float* Wt1  = (const float*)d_in[3];
  const float* bt1  = (const float*)d_in[4];
  const float* Wt2  = (const float*)d_in[5];
  const float* bt2  = (const float*)d_in[6];
  const float* Win0 = (const float*)d_in[7];
  const float* bin0 = (const float*)d_in[8];
  const float* Win1 = (const float*)d_in[9];
  const float* Wqkv = (const float*)d_in[10];
  const float* Wr1  = (const float*)d_in[11];
  const float* br1  = (const float*)d_in[12];
  const float* Wr2  = (const float*)d_in[13];
  const float* br2  = (const float*)d_in[14];
  const float* Wo   = (const float*)d_in[15];
  const float* bo   = (const float*)d_in[16];
  const float* Wout = (const float*)d_in[17];
  const float* bout = (const float*)d_in[18];
  float* out = (float*)d_out;

  char* wsb = (char*)d_ws;
  size_t off = 0;
  auto alloc = [&](size_t bytes) -> void* {
    void* p = wsb + off;
    off = (off + bytes + 255) & ~(size_t)255;
    return p;
  };
  const int totalNodes = NBATCH * NPTS;  // 8192
  float* pre0 = (float*)alloc((size_t)NBATCH * CC * 4);
  float* f0   = (float*)alloc((size_t)totalNodes * CC * 4);
  float* f1   = (float*)alloc((size_t)totalNodes * 3 * CC * 4);
  _Float16* f0h = (_Float16*)alloc((size_t)totalNodes * CC * 2);
  _Float16* f1h = (_Float16*)alloc((size_t)totalNodes * 3 * CC * 2);
  _Float16* Whq = (_Float16*)alloc((size_t)NL * 12 * CC * HD_ * 2);
  int*   idx  = (int*)alloc((size_t)totalNodes * KNN * 4);
  float* rhat = (float*)alloc((size_t)totalNodes * KNN * 3 * 4);
  float* rl   = (float*)alloc((size_t)totalNodes * KNN * 4);
  size_t fixedBytes = off;
  size_t perBatch = (size_t)NPTS * ((640 + 2688) * 2 + (128 + 384) * 4);
  int nbg = 8;
  while (nbg > 1 && fixedBytes + (size_t)nbg * perBatch + 8192 > ws_size) nbg >>= 1;
  _Float16* P0 = (_Float16*)alloc((size_t)nbg * NPTS * 640 * 2);
  _Float16* P1 = (_Float16*)alloc((size_t)nbg * NPTS * 2688 * 2);
  float* o0b = (float*)alloc((size_t)nbg * NPTS * 128 * 4);
  float* o1b = (float*)alloc((size_t)nbg * NPTS * 384 * 4);

  k_temb<<<NBATCH, 128, 0, stream>>>(t, Wt1, bt1, Wt2, bt2, Win0, bin0, pre0);
  k_init<<<totalNodes / 2, 256, 0, stream>>>(x, Win0, Win1, pre0, f0, f1, f0h, f1h);
  k_knn<<<NBATCH * 32, 256, 0, stream>>>(x, idx, rhat, rl);
  k_wconv<<<NL * 12, 256, 0, stream>>>(Wqkv, Whq);

  for (int g = 0; g < NBATCH / nbg; ++g) {
    int nodeBase = g * nbg * NPTS;
    int nodes = nbg * NPTS;
    int nb0 = nodes / 128;
    for (int l = 0; l < NL; ++l) {
      k_proj_mfma<<<nb0 * 26, 256, 0, stream>>>(
          f0h + (size_t)nodeBase * CC, f1h + (size_t)nodeBase * 3 * CC,
          Whq + (size_t)l * 12 * CC * HD_, P0, P1, nb0);
      k_attn<<<nodes, 128, 0, stream>>>(
          P0, P1, idx, rhat, rl, Wr1, br1, Wr2, br2, o0b, o1b, nodeBase, l, nbg);
      k_wo<<<nb0 * 4, 256, 0, stream>>>(
          o0b, o1b, Wo + (size_t)(l * 2) * HD_ * CC, bo + (size_t)(l * 2) * CC,
          f0 + (size_t)nodeBase * CC, f1 + (size_t)nodeBase * 3 * CC,
          f0h + (size_t)nodeBase * CC, f1h + (size_t)nodeBase * 3 * CC, nb0);
    }
  }
  k_out<<<(totalNodes * 3) / 256, 256, 0, stream>>>(f1, Wout, bout, out);
}

// Round 6
// 469.648 us; speedup vs baseline: 2.5662x; 1.1727x over previous
//
#include <hip/hip_runtime.h>
#include <math.h>

#define NBATCH 8
#define NPTS   1024
#define KNN    8
#define CC     128
#define HD_    128
#define TED_   128
#define TEC_   64
#define RH     32
#define NL     4

typedef _Float16 half8 __attribute__((ext_vector_type(8)));
typedef _Float16 h2v  __attribute__((ext_vector_type(2)));
typedef float f32x4 __attribute__((ext_vector_type(4)));

// ---------------------------------------------------------------- temb
__global__ __launch_bounds__(128) void k_temb(
    const float* __restrict__ t, const float* __restrict__ Wt1,
    const float* __restrict__ bt1, const float* __restrict__ Wt2,
    const float* __restrict__ bt2, const float* __restrict__ Win0,
    const float* __restrict__ bin0, float* __restrict__ pre0)
{
  int b = blockIdx.x;
  int tid = threadIdx.x;
  __shared__ float e128[TED_];
  __shared__ float h1[TED_];
  __shared__ float te[TEC_];
  float tv = t[b];
  if (tid < 64) {
    float fr = expf((-9.210340371976184f * (float)tid) * 0.015625f);
    float em = tv * fr;
    e128[tid]      = sinf(em);
    e128[tid + 64] = cosf(em);
  }
  __syncthreads();
  {
    float acc = bt1[tid];
    for (int i = 0; i < TED_; ++i) acc += e128[i] * Wt1[i * TED_ + tid];
    h1[tid] = acc / (1.0f + expf(-acc));
  }
  __syncthreads();
  if (tid < TEC_) {
    float acc = bt2[tid];
    for (int j = 0; j < TED_; ++j) acc += h1[j] * Wt2[j * TEC_ + tid];
    te[tid] = acc;
  }
  __syncthreads();
  {
    float acc = bin0[tid];
    for (int i = 0; i < TEC_; ++i) acc += te[i] * Win0[i * CC + tid];
    pre0[b * CC + tid] = acc;
  }
}

// ---------------------------------------------------------------- init f0/f1 (+fp16 copies)
__global__ __launch_bounds__(256) void k_init(
    const float* __restrict__ x, const float* __restrict__ Win0,
    const float* __restrict__ Win1, const float* __restrict__ pre0,
    float* __restrict__ f0, float* __restrict__ f1,
    _Float16* __restrict__ f0h, _Float16* __restrict__ f1h)
{
  int node = blockIdx.x * 2 + (threadIdx.x >> 7);
  int c = threadIdx.x & 127;
  int b = node >> 10;
  float x0 = x[node * 3 + 0], x1 = x[node * 3 + 1], x2 = x[node * 3 + 2];
  float acc = pre0[b * CC + c]
            + x0 * Win0[(TEC_ + 0) * CC + c]
            + x1 * Win0[(TEC_ + 1) * CC + c]
            + x2 * Win0[(TEC_ + 2) * CC + c];
  f0[(size_t)node * CC + c] = acc;
  f0h[(size_t)node * CC + c] = (_Float16)acc;
  float w1 = Win1[c];
  float v0 = x0 * w1, v1 = x1 * w1, v2 = x2 * w1;
  f1[((size_t)node * 3 + 0) * CC + c] = v0;
  f1[((size_t)node * 3 + 1) * CC + c] = v1;
  f1[((size_t)node * 3 + 2) * CC + c] = v2;
  f1h[((size_t)node * 3 + 0) * CC + c] = (_Float16)v0;
  f1h[((size_t)node * 3 + 1) * CC + c] = (_Float16)v1;
  f1h[((size_t)node * 3 + 2) * CC + c] = (_Float16)v2;
}

// ---------------------------------------------------------------- knn
__global__ __launch_bounds__(256) void k_knn(
    const float* __restrict__ x, int* __restrict__ idx,
    float* __restrict__ rhat, float* __restrict__ rl)
{
  const int b    = blockIdx.x >> 5;
  const int tile = blockIdx.x & 31;
  const int tid  = threadIdx.x;
  const int qg   = tid >> 3;
  const int sub  = tid & 7;

  __shared__ float xs[NPTS * 3];
  __shared__ unsigned long long keys[32][64];

  for (int i = tid; i < NPTS * 3; i += 256) xs[i] = x[(size_t)b * NPTS * 3 + i];
  __syncthreads();

  const int n = tile * 32 + qg;
  const float qx = xs[n * 3 + 0], qy = xs[n * 3 + 1], qz = xs[n * 3 + 2];

  unsigned long long bd[KNN];
  #pragma unroll
  for (int k = 0; k < KNN; ++k) bd[k] = ~0ull;

  const int j0 = sub * 128;
  for (int j = j0; j < j0 + 128; ++j) {
    float dx = qx - xs[j * 3 + 0];
    float dy = qy - xs[j * 3 + 1];
    float dz = qz - xs[j * 3 + 2];
    float s = __fadd_rn(__fadd_rn(__fmul_rn(dx, dx), __fmul_rn(dy, dy)),
                        __fmul_rn(dz, dz));
    if (j == n) s = 1.0e9f;
    unsigned long long key =
        ((unsigned long long)__float_as_uint(s) << 32) | (unsigned int)j;
    if (key < bd[KNN - 1]) {
      bd[KNN - 1] = key;
      #pragma unroll
      for (int q = KNN - 1; q > 0; --q) {
        if (bd[q] < bd[q - 1]) {
          unsigned long long tmp = bd[q]; bd[q] = bd[q - 1]; bd[q - 1] = tmp;
        }
      }
    }
  }
  #pragma unroll
  for (int k = 0; k < KNN; ++k) keys[qg][sub * KNN + k] = bd[k];
  __syncthreads();

  if (sub == 0) {
    unsigned long long m[KNN];
    #pragma unroll
    for (int k = 0; k < KNN; ++k) m[k] = ~0ull;
    for (int i = 0; i < 64; ++i) {
      unsigned long long key = keys[qg][i];
      if (key < m[KNN - 1]) {
        m[KNN - 1] = key;
        #pragma unroll
        for (int q = KNN - 1; q > 0; --q) {
          if (m[q] < m[q - 1]) {
            unsigned long long tmp = m[q]; m[q] = m[q - 1]; m[q - 1] = tmp;
          }
        }
      }
    }
    size_t base = ((size_t)b * NPTS + n) * KNN;
    #pragma unroll
    for (int k = 0; k < KNN; ++k) {
      int j = (int)(m[k] & 0xffffffffu);
      idx[base + k] = j;
      float rx = xs[j * 3 + 0] - qx;
      float ry = xs[j * 3 + 1] - qy;
      float rz = xs[j * 3 + 2] - qz;
      float rr2 = rx * rx + ry * ry + rz * rz + 1e-8f;
      float r = sqrtf(rr2);
      rl[base + k] = r;
      rhat[(base + k) * 3 + 0] = rx / r;
      rhat[(base + k) * 3 + 1] = ry / r;
      rhat[(base + k) * 3 + 2] = rz / r;
    }
  }
}

// ---------------------------------------------------------------- W convert+transpose (once)
// 48 Wqkv mats + 8 Wo mats, each [128k][128n] fp32 -> [128n][128k] fp16
__global__ __launch_bounds__(256) void k_wconv(
    const float* __restrict__ Wqkv, const float* __restrict__ Wo,
    _Float16* __restrict__ Whq, _Float16* __restrict__ Who)
{
  __shared__ _Float16 T[128][136];
  int m = blockIdx.x;
  const float* src; _Float16* dst;
  if (m < 48) { src = Wqkv + (size_t)m * 16384; dst = Whq + (size_t)m * 16384; }
  else { src = Wo + (size_t)(m - 48) * 16384; dst = Who + (size_t)(m - 48) * 16384; }
  int tid = threadIdx.x;
  for (int i = tid; i < 16384; i += 256) {
    int k = i >> 7, n = i & 127;
    T[n][k] = (_Float16)src[i];
  }
  __syncthreads();
  for (int i = tid; i < 16384; i += 256) {
    int n = i >> 7, k = i & 127;
    dst[i] = T[n][k];
  }
}

// ---------------------------------------------------------------- MFMA tile body (128x128x128)
// defines: tid, lane, w, r15, g, acc[8][2]
#define MFMA_BODY(A_, ROWBASE_, WT_)                                          \
  const int tid  = threadIdx.x;                                               \
  const int lane = tid & 63;                                                  \
  const int w    = tid >> 6;                                                  \
  const int r15  = lane & 15;                                                 \
  const int g    = lane >> 4;                                                 \
  half8 bf[2][4];                                                             \
  _Pragma("unroll")                                                           \
  for (int ntl = 0; ntl < 2; ++ntl) {                                         \
    int n = (w * 2 + ntl) * 16 + r15;                                         \
    const _Float16* wp = (WT_) + (size_t)n * 128 + g * 8;                     \
    _Pragma("unroll")                                                         \
    for (int ks = 0; ks < 4; ++ks)                                            \
      bf[ntl][ks] = *(const half8*)(wp + ks * 32);                            \
  }                                                                           \
  {                                                                           \
    int r = tid >> 1;                                                         \
    const _Float16* src = (A_) + (size_t)((ROWBASE_) + r) * 128;              \
    int c0 = (tid & 1) * 8;                                                   \
    _Pragma("unroll")                                                         \
    for (int q = 0; q < 8; ++q) {                                             \
      int c = c0 + q;                                                         \
      *(uint4*)&As[r][c * 8] = *(const uint4*)(src + c * 8);                  \
    }                                                                         \
  }                                                                           \
  __syncthreads();                                                            \
  f32x4 acc[8][2] = {};                                                       \
  _Pragma("unroll")                                                           \
  for (int ks = 0; ks < 4; ++ks) {                                            \
    half8 a[8];                                                               \
    _Pragma("unroll")                                                         \
    for (int mt = 0; mt < 8; ++mt)                                            \
      a[mt] = *(const half8*)&As[mt * 16 + r15][ks * 32 + g * 8];             \
    _Pragma("unroll")                                                         \
    for (int mt = 0; mt < 8; ++mt) {                                          \
      acc[mt][0] = __builtin_amdgcn_mfma_f32_16x16x32_f16(a[mt], bf[0][ks], acc[mt][0], 0, 0, 0); \
      acc[mt][1] = __builtin_amdgcn_mfma_f32_16x16x32_f16(a[mt], bf[1][ks], acc[mt][1], 0, 0, 0); \
    }                                                                         \
  }

// ---------------------------------------------------------------- proj MFMA
__global__ __launch_bounds__(256) void k_proj_mfma(
    const _Float16* __restrict__ f0h, const _Float16* __restrict__ f1h,
    const _Float16* __restrict__ Wh, _Float16* __restrict__ P0,
    _Float16* __restrict__ P1, int nb0)
{
  __shared__ _Float16 As[128][136];
  int z = blockIdx.x;
  const _Float16* A; const _Float16* Wt; _Float16* P; int ldP, colBase, rowBase;
  if (z < nb0 * 5) {
    const int map0[5] = {0, 2, 4, 7, 9};
    int m = z / nb0, rb = z - m * nb0;
    A = f0h; rowBase = rb * 128;
    Wt = Wh + (size_t)map0[m] * 16384;
    P = P0; ldP = 640; colBase = m * 128;
  } else {
    z -= nb0 * 5;
    int nb1 = nb0 * 3;
    const int map1[7] = {1, 3, 5, 6, 8, 10, 11};
    int m = z / nb1, rb = z - m * nb1;
    A = f1h; rowBase = rb * 128;
    Wt = Wh + (size_t)map1[m] * 16384;
    P = P1; ldP = 896; colBase = m * 128;
  }
  MFMA_BODY(A, rowBase, Wt)
  #pragma unroll
  for (int mt = 0; mt < 8; ++mt) {
    #pragma unroll
    for (int ntl = 0; ntl < 2; ++ntl) {
      int col = colBase + (w * 2 + ntl) * 16 + r15;
      #pragma unroll
      for (int i = 0; i < 4; ++i) {
        int r = rowBase + mt * 16 + g * 4 + i;
        P[(size_t)r * ldP + col] = (_Float16)acc[mt][ntl][i];
      }
    }
  }
}

// ---------------------------------------------------------------- Wo MFMA + residual
__global__ __launch_bounds__(256) void k_wo_mfma(
    const _Float16* __restrict__ o0h, const _Float16* __restrict__ o1h,
    const _Float16* __restrict__ Who_l, const float* __restrict__ bo_l,
    float* __restrict__ f0, float* __restrict__ f1,
    _Float16* __restrict__ f0h, _Float16* __restrict__ f1h, int nb0)
{
  __shared__ _Float16 As[128][136];
  int z = blockIdx.x;
  const _Float16* A; const _Float16* Wt; const float* bias;
  float* F; _Float16* FH; int rowBase;
  if (z < nb0) {
    A = o0h; Wt = Who_l; bias = bo_l; F = f0; FH = f0h; rowBase = z * 128;
  } else {
    z -= nb0;
    A = o1h; Wt = Who_l + 16384; bias = bo_l + CC; F = f1; FH = f1h; rowBase = z * 128;
  }
  MFMA_BODY(A, rowBase, Wt)
  #pragma unroll
  for (int mt = 0; mt < 8; ++mt) {
    #pragma unroll
    for (int ntl = 0; ntl < 2; ++ntl) {
      int col = (w * 2 + ntl) * 16 + r15;
      float bv = bias[col];
      #pragma unroll
      for (int i = 0; i < 4; ++i) {
        int r = rowBase + mt * 16 + g * 4 + i;
        size_t p = (size_t)r * 128 + col;
        float val = F[p] + acc[mt][ntl][i] + bv;
        F[p] = val;
        FH[p] = (_Float16)val;
      }
    }
  }
}

// ---------------------------------------------------------------- attn v3
// 64 lanes per node (2 channels/lane), 4 nodes per 256-thread block,
// online softmax, fp16 h2v gathers, fp16 output.
__global__ __launch_bounds__(256) void k_attn(
    const _Float16* __restrict__ P0, const _Float16* __restrict__ P1,
    const int* __restrict__ idx, const float* __restrict__ rhat,
    const float* __restrict__ rl,
    const float* __restrict__ Wr1, const float* __restrict__ br1,
    const float* __restrict__ Wr2, const float* __restrict__ br2,
    _Float16* __restrict__ o0h, _Float16* __restrict__ o1h,
    int nodeBase, int layer, int nbg)
{
  const int t = threadIdx.x;
  const int wv = t >> 6;
  const int lane = t & 63;
  const int z = blockIdx.x;
  const int bb = z % nbg;
  const int nodeLocal = bb * NPTS + (z / nbg) * 4 + wv;
  const int node = nodeBase + nodeLocal;
  const int batchRow = bb * NPTS;

  __shared__ float rn_s[4][KNN][80];
  __shared__ float hid_s[4][KNN][RH];
  __shared__ float rh_s[4][KNN][3];
  __shared__ float rl_s[4][KNN];

  if (lane < KNN * 3) rh_s[wv][lane / 3][lane % 3] = rhat[(size_t)node * KNN * 3 + lane];
  if (lane >= 32 && lane < 32 + KNN) rl_s[wv][lane - 32] = rl[(size_t)node * KNN + (lane - 32)];
  __syncthreads();

  const float* wr1 = Wr1 + layer * RH;
  const float* wb1 = br1 + layer * RH;
  #pragma unroll
  for (int u = 0; u < 4; ++u) {
    int f = u * 64 + lane;          // 256 = KNN*RH
    int k = f >> 5, i = f & 31;
    float zv = rl_s[wv][k] * wr1[i] + wb1[i];
    hid_s[wv][k][i] = zv / (1.0f + expf(-zv));
  }
  __syncthreads();
  const float* wr2 = Wr2 + layer * RH * 80;
  const float* wb2 = br2 + layer * 80;
  #pragma unroll
  for (int u = 0; u < 10; ++u) {
    int f = u * 64 + lane;          // 640 = KNN*80
    int k = f / 80, col = f - k * 80;
    float acc = wb2[col];
    #pragma unroll
    for (int i = 0; i < RH; ++i) acc += hid_s[wv][k][i] * wr2[i * 80 + col];
    rn_s[wv][k][col] = acc;
  }
  __syncthreads();

  const int c0 = lane * 2;
  const int h = lane >> 3;
  const _Float16* p0n = P0 + (size_t)nodeLocal * 640 + c0;
  const _Float16* p1n = P1 + (size_t)nodeLocal * 2688 + c0;
  h2v q0v  = *(const h2v*)(p0n);
  h2v q1xv = *(const h2v*)(p1n);
  h2v q1yv = *(const h2v*)(p1n + 896);
  h2v q1zv = *(const h2v*)(p1n + 1792);

  const float inv_scale = 0.17677669529663687f;  // 1/sqrt(32)
  const int* idxp = idx + (size_t)node * KNN;

  float m = -3.0e38f, ssum = 0.0f;
  float a0[2] = {}, ax[2] = {}, ay[2] = {}, az[2] = {};

  for (int k = 0; k < KNN; ++k) {
    int jl = batchRow + idxp[k];
    const _Float16* g0 = P0 + (size_t)jl * 640 + c0;
    const _Float16* g1 = P1 + (size_t)jl * 2688 + c0;
    float rx = rh_s[wv][k][0], ry = rh_s[wv][k][1], rz = rh_s[wv][k][2];

    h2v G02 = *(const h2v*)(g0 + 128), G04 = *(const h2v*)(g0 + 256);
    h2v G07 = *(const h2v*)(g0 + 384), G09 = *(const h2v*)(g0 + 512);
    h2v G13x = *(const h2v*)(g1 + 128),  G13y = *(const h2v*)(g1 + 896 + 128),  G13z = *(const h2v*)(g1 + 1792 + 128);
    h2v G15x = *(const h2v*)(g1 + 256),  G15y = *(const h2v*)(g1 + 896 + 256),  G15z = *(const h2v*)(g1 + 1792 + 256);
    h2v G16x = *(const h2v*)(g1 + 384),  G16y = *(const h2v*)(g1 + 896 + 384),  G16z = *(const h2v*)(g1 + 1792 + 384);
    h2v G18x = *(const h2v*)(g1 + 512),  G18y = *(const h2v*)(g1 + 896 + 512),  G18z = *(const h2v*)(g1 + 1792 + 512);
    h2v G1Ax = *(const h2v*)(g1 + 640),  G1Ay = *(const h2v*)(g1 + 896 + 640),  G1Az = *(const h2v*)(g1 + 1792 + 640);
    h2v G1Bx = *(const h2v*)(g1 + 768),  G1By = *(const h2v*)(g1 + 896 + 768),  G1Bz = *(const h2v*)(g1 + 1792 + 768);

    const float* rnh = &rn_s[wv][k][h * 10];
    float r0 = rnh[0], r1 = rnh[1], r2 = rnh[2], r3 = rnh[3], r4 = rnh[4];
    float r5 = rnh[5], r6 = rnh[6], r7 = rnh[7], r8 = rnh[8], r9 = rnh[9];

    float pl = 0.0f;
    float v0c[2], vxc[2], vyc[2], vzc[2];
    #pragma unroll
    for (int ci = 0; ci < 2; ++ci) {
      float g02 = (float)G02[ci], g04 = (float)G04[ci];
      float g07 = (float)G07[ci], g09 = (float)G09[ci];
      float g13x = (float)G13x[ci], g13y = (float)G13y[ci], g13z = (float)G13z[ci];
      float g15x = (float)G15x[ci], g15y = (float)G15y[ci], g15z = (float)G15z[ci];
      float g16x = (float)G16x[ci], g16y = (float)G16y[ci], g16z = (float)G16z[ci];
      float g18x = (float)G18x[ci], g18y = (float)G18y[ci], g18z = (float)G18z[ci];
      float g1ax = (float)G1Ax[ci], g1ay = (float)G1Ay[ci], g1az = (float)G1Az[ci];
      float g1bx = (float)G1Bx[ci], g1by = (float)G1By[ci], g1bz = (float)G1Bz[ci];

      float DP3 = g13x * rx + g13y * ry + g13z * rz;
      float DP6 = g16x * rx + g16y * ry + g16z * rz;
      float DP8 = g18x * rx + g18y * ry + g18z * rz;
      float DPB = g1bx * rx + g1by * ry + g1bz * rz;

      float k0  = g02 * r0 + DP3 * r1;
      float k1x = g04 * rx * r2 + g15x * r3 + (3.0f * rx * DP6 - g16x) * r4;
      float k1y = g04 * ry * r2 + g15y * r3 + (3.0f * ry * DP6 - g16y) * r4;
      float k1z = g04 * rz * r2 + g15z * r3 + (3.0f * rz * DP6 - g16z) * r4;
      v0c[ci] = g07 * r5 + DP8 * r6;
      vxc[ci] = g09 * rx * r7 + g1ax * r8 + (3.0f * rx * DPB - g1bx) * r9;
      vyc[ci] = g09 * ry * r7 + g1ay * r8 + (3.0f * ry * DPB - g1by) * r9;
      vzc[ci] = g09 * rz * r7 + g1az * r8 + (3.0f * rz * DPB - g1bz) * r9;

      pl += (float)((ci == 0) ? q0v[0] : q0v[1]) * k0
          + (float)((ci == 0) ? q1xv[0] : q1xv[1]) * k1x
          + (float)((ci == 0) ? q1yv[0] : q1yv[1]) * k1y
          + (float)((ci == 0) ? q1zv[0] : q1zv[1]) * k1z;
    }
    pl += __shfl_xor(pl, 1, 8);
    pl += __shfl_xor(pl, 2, 8);
    pl += __shfl_xor(pl, 4, 8);
    pl *= inv_scale;

    float mnew = fmaxf(m, pl);
    float scale = expf(m - mnew);
    float wgt = expf(pl - mnew);
    ssum = ssum * scale + wgt;
    #pragma unroll
    for (int ci = 0; ci < 2; ++ci) {
      a0[ci] = a0[ci] * scale + wgt * v0c[ci];
      ax[ci] = ax[ci] * scale + wgt * vxc[ci];
      ay[ci] = ay[ci] * scale + wgt * vyc[ci];
      az[ci] = az[ci] * scale + wgt * vzc[ci];
    }
    m = mnew;
  }

  float invs = 1.0f / ssum;
  h2v o;
  o[0] = (_Float16)(a0[0] * invs); o[1] = (_Float16)(a0[1] * invs);
  *(h2v*)(o0h + (size_t)nodeLocal * 128 + c0) = o;
  o[0] = (_Float16)(ax[0] * invs); o[1] = (_Float16)(ax[1] * invs);
  *(h2v*)(o1h + ((size_t)nodeLocal * 3 + 0) * 128 + c0) = o;
  o[0] = (_Float16)(ay[0] * invs); o[1] = (_Float16)(ay[1] * invs);
  *(h2v*)(o1h + ((size_t)nodeLocal * 3 + 1) * 128 + c0) = o;
  o[0] = (_Float16)(az[0] * invs); o[1] = (_Float16)(az[1] * invs);
  *(h2v*)(o1h + ((size_t)nodeLocal * 3 + 2) * 128 + c0) = o;
}

// ---------------------------------------------------------------- final out
__global__ __launch_bounds__(256) void k_out(
    const float* __restrict__ f1, const float* __restrict__ Wout,
    const float* __restrict__ bout, float* __restrict__ out)
{
  int i = blockIdx.x * 256 + threadIdx.x;
  int v = i % 3;
  const float* row = f1 + (size_t)i * CC;
  const float* w = Wout + v * CC;
  float acc = 0.0f;
  #pragma unroll
  for (int c = 0; c < CC; c += 4) {
    float4 fv = *(const float4*)&row[c];
    float4 wv = *(const float4*)&w[c];
    acc += fv.x * wv.x + fv.y * wv.y + fv.z * wv.z + fv.w * wv.w;
  }
  out[i] = acc + bout[v];
}

// ---------------------------------------------------------------- host
extern "C" void kernel_launch(void* const* d_in, const int* in_sizes, int n_in,
                              void* d_out, int out_size, void* d_ws, size_t ws_size,
                              hipStream_t stream) {
  const float* x    = (const float*)d_in[0];
  const float* t    = (const float*)d_in[2];
  const float* Wt1  = (const float*)d_in[3];
  const float* bt1  = (const float*)d_in[4];
  const float* Wt2  = (const float*)d_in[5];
  const float* bt2  = (const float*)d_in[6];
  const float* Win0 = (const float*)d_in[7];
  const float* bin0 = (const float*)d_in[8];
  const float* Win1 = (const float*)d_in[9];
  const float* Wqkv = (const float*)d_in[10];
  const float* Wr1  = (const float*)d_in[11];
  const float* br1  = (const float*)d_in[12];
  const float* Wr2  = (const float*)d_in[13];
  const float* br2  = (const float*)d_in[14];
  const float* Wo   = (const float*)d_in[15];
  const float* bo   = (const float*)d_in[16];
  const float* Wout = (const float*)d_in[17];
  const float* bout = (const float*)d_in[18];
  float* out = (float*)d_out;

  char* wsb = (char*)d_ws;
  size_t off = 0;
  auto alloc = [&](size_t bytes) -> void* {
    void* p = wsb + off;
    off = (off + bytes + 255) & ~(size_t)255;
    return p;
  };
  const int totalNodes = NBATCH * NPTS;  // 8192
  float* pre0 = (float*)alloc((size_t)NBATCH * CC * 4);
  float* f0   = (float*)alloc((size_t)totalNodes * CC * 4);
  float* f1   = (float*)alloc((size_t)totalNodes * 3 * CC * 4);
  _Float16* f0h = (_Float16*)alloc((size_t)totalNodes * CC * 2);
  _Float16* f1h = (_Float16*)alloc((size_t)totalNodes * 3 * CC * 2);
  _Float16* Whq = (_Float16*)alloc((size_t)NL * 12 * CC * HD_ * 2);
  _Float16* Who = (_Float16*)alloc((size_t)NL * 2 * CC * HD_ * 2);
  int*   idx  = (int*)alloc((size_t)totalNodes * KNN * 4);
  float* rhat = (float*)alloc((size_t)totalNodes * KNN * 3 * 4);
  float* rl   = (float*)alloc((size_t)totalNodes * KNN * 4);
  size_t fixedBytes = off;
  // per batch: P 3328*2B + o 512*2B per node
  size_t perBatch = (size_t)NPTS * ((640 + 2688) * 2 + (128 + 384) * 2);
  int nbg = 8;
  while (nbg > 1 && fixedBytes + (size_t)nbg * perBatch + 8192 > ws_size) nbg >>= 1;
  _Float16* P0  = (_Float16*)alloc((size_t)nbg * NPTS * 640 * 2);
  _Float16* P1  = (_Float16*)alloc((size_t)nbg * NPTS * 2688 * 2);
  _Float16* o0h = (_Float16*)alloc((size_t)nbg * NPTS * 128 * 2);
  _Float16* o1h = (_Float16*)alloc((size_t)nbg * NPTS * 384 * 2);

  k_temb<<<NBATCH, 128, 0, stream>>>(t, Wt1, bt1, Wt2, bt2, Win0, bin0, pre0);
  k_init<<<totalNodes / 2, 256, 0, stream>>>(x, Win0, Win1, pre0, f0, f1, f0h, f1h);
  k_knn<<<NBATCH * 32, 256, 0, stream>>>(x, idx, rhat, rl);
  k_wconv<<<56, 256, 0, stream>>>(Wqkv, Wo, Whq, Who);

  for (int g = 0; g < NBATCH / nbg; ++g) {
    int nodeBase = g * nbg * NPTS;
    int nodes = nbg * NPTS;
    int nb0 = nodes / 128;
    for (int l = 0; l < NL; ++l) {
      k_proj_mfma<<<nb0 * 26, 256, 0, stream>>>(
          f0h + (size_t)nodeBase * CC, f1h + (size_t)nodeBase * 3 * CC,
          Whq + (size_t)l * 12 * CC * HD_, P0, P1, nb0);
      k_attn<<<nodes / 4, 256, 0, stream>>>(
          P0, P1, idx, rhat, rl, Wr1, br1, Wr2, br2, o0h, o1h, nodeBase, l, nbg);
      k_wo_mfma<<<nb0 * 4, 256, 0, stream>>>(
          o0h, o1h, Who + (size_t)l * 2 * CC * HD_, bo + (size_t)(l * 2) * CC,
          f0 + (size_t)nodeBase * CC, f1 + (size_t)nodeBase * 3 * CC,
          f0h + (size_t)nodeBase * CC, f1h + (size_t)nodeBase * 3 * CC, nb0);
    }
  }
  k_out<<<(totalNodes * 3) / 256, 256, 0, stream>>>(f1, Wout, bout, out);
}

// Round 7
// 463.943 us; speedup vs baseline: 2.5978x; 1.0123x over previous
//
#include <hip/hip_runtime.h>
#include <math.h>

#define NBATCH 8
#define NPTS   1024
#define KNN    8
#define CC     128
#define HD_    128
#define TED_   128
#define TEC_   64
#define RH     32
#define NL     4

typedef _Float16 half8 __attribute__((ext_vector_type(8)));
typedef _Float16 h4v  __attribute__((ext_vector_type(4)));
typedef float f32x4 __attribute__((ext_vector_type(4)));

__device__ __forceinline__ unsigned long long shflxor_u64(unsigned long long v, int m) {
  return (unsigned long long)__shfl_xor((long long)v, m, 8);
}

// ---------------------------------------------------------------- temb
__global__ __launch_bounds__(128) void k_temb(
    const float* __restrict__ t, const float* __restrict__ Wt1,
    const float* __restrict__ bt1, const float* __restrict__ Wt2,
    const float* __restrict__ bt2, const float* __restrict__ Win0,
    const float* __restrict__ bin0, float* __restrict__ pre0)
{
  int b = blockIdx.x;
  int tid = threadIdx.x;
  __shared__ float e128[TED_];
  __shared__ float h1[TED_];
  __shared__ float te[TEC_];
  float tv = t[b];
  if (tid < 64) {
    float fr = expf((-9.210340371976184f * (float)tid) * 0.015625f);
    float em = tv * fr;
    e128[tid]      = sinf(em);
    e128[tid + 64] = cosf(em);
  }
  __syncthreads();
  {
    float acc = bt1[tid];
    for (int i = 0; i < TED_; ++i) acc += e128[i] * Wt1[i * TED_ + tid];
    h1[tid] = acc / (1.0f + expf(-acc));
  }
  __syncthreads();
  if (tid < TEC_) {
    float acc = bt2[tid];
    for (int j = 0; j < TED_; ++j) acc += h1[j] * Wt2[j * TEC_ + tid];
    te[tid] = acc;
  }
  __syncthreads();
  {
    float acc = bin0[tid];
    for (int i = 0; i < TEC_; ++i) acc += te[i] * Win0[i * CC + tid];
    pre0[b * CC + tid] = acc;
  }
}

// ---------------------------------------------------------------- init f0/f1 (+fp16 copies)
__global__ __launch_bounds__(256) void k_init(
    const float* __restrict__ x, const float* __restrict__ Win0,
    const float* __restrict__ Win1, const float* __restrict__ pre0,
    float* __restrict__ f0, float* __restrict__ f1,
    _Float16* __restrict__ f0h, _Float16* __restrict__ f1h)
{
  int node = blockIdx.x * 2 + (threadIdx.x >> 7);
  int c = threadIdx.x & 127;
  int b = node >> 10;
  float x0 = x[node * 3 + 0], x1 = x[node * 3 + 1], x2 = x[node * 3 + 2];
  float acc = pre0[b * CC + c]
            + x0 * Win0[(TEC_ + 0) * CC + c]
            + x1 * Win0[(TEC_ + 1) * CC + c]
            + x2 * Win0[(TEC_ + 2) * CC + c];
  f0[(size_t)node * CC + c] = acc;
  f0h[(size_t)node * CC + c] = (_Float16)acc;
  float w1 = Win1[c];
  float v0 = x0 * w1, v1 = x1 * w1, v2 = x2 * w1;
  f1[((size_t)node * 3 + 0) * CC + c] = v0;
  f1[((size_t)node * 3 + 1) * CC + c] = v1;
  f1[((size_t)node * 3 + 2) * CC + c] = v2;
  f1h[((size_t)node * 3 + 0) * CC + c] = (_Float16)v0;
  f1h[((size_t)node * 3 + 1) * CC + c] = (_Float16)v1;
  f1h[((size_t)node * 3 + 2) * CC + c] = (_Float16)v2;
}

// ---------------------------------------------------------------- knn v3
// SoA xs + per-sub bank stagger (conflict-free), wave-parallel extract-min merge.
__global__ __launch_bounds__(256) void k_knn(
    const float* __restrict__ x, int* __restrict__ idx,
    float* __restrict__ rhat, float* __restrict__ rl)
{
  const int b    = blockIdx.x >> 5;
  const int tile = blockIdx.x & 31;
  const int tid  = threadIdx.x;
  const int qg   = tid >> 3;
  const int sub  = tid & 7;

  __shared__ float xsx[NPTS], xsy[NPTS], xsz[NPTS];

  for (int i = tid; i < NPTS; i += 256) {
    const float* xp = x + ((size_t)b * NPTS + i) * 3;
    xsx[i] = xp[0]; xsy[i] = xp[1]; xsz[i] = xp[2];
  }
  __syncthreads();

  const int n = tile * 32 + qg;
  const float qx = xsx[n], qy = xsy[n], qz = xsz[n];

  unsigned long long bd[KNN];
  #pragma unroll
  for (int k = 0; k < KNN; ++k) bd[k] = ~0ull;

  const int j0 = sub * 128;
  const int ph = sub * 4;          // bank stagger: (it + 4*sub) % 32 distinct per sub
  for (int it = 0; it < 128; ++it) {
    int j = j0 + ((it + ph) & 127);
    float dx = qx - xsx[j];
    float dy = qy - xsy[j];
    float dz = qz - xsz[j];
    float s = __fadd_rn(__fadd_rn(__fmul_rn(dx, dx), __fmul_rn(dy, dy)),
                        __fmul_rn(dz, dz));
    if (j == n) s = 1.0e9f;
    unsigned long long key =
        ((unsigned long long)__float_as_uint(s) << 32) | (unsigned int)j;
    if (key < bd[KNN - 1]) {
      bd[KNN - 1] = key;
      #pragma unroll
      for (int q = KNN - 1; q > 0; --q) {
        if (bd[q] < bd[q - 1]) {
          unsigned long long tmp = bd[q]; bd[q] = bd[q - 1]; bd[q - 1] = tmp;
        }
      }
    }
  }

  // wave-parallel merge: 8 rounds of extract-min across the 8 subs
  unsigned long long res[KNN];
  #pragma unroll
  for (int r = 0; r < KNN; ++r) {
    unsigned long long m = bd[0];
    unsigned long long o;
    o = shflxor_u64(m, 1); m = (o < m) ? o : m;
    o = shflxor_u64(m, 2); m = (o < m) ? o : m;
    o = shflxor_u64(m, 4); m = (o < m) ? o : m;
    if (bd[0] == m) {
      #pragma unroll
      for (int q = 0; q < KNN - 1; ++q) bd[q] = bd[q + 1];
      bd[KNN - 1] = ~0ull;
    }
    res[r] = m;
  }

  // lane `sub` writes neighbor `sub`
  unsigned long long key = res[0];
  #pragma unroll
  for (int r = 1; r < KNN; ++r) if (sub == r) key = res[r];
  int j = (int)(key & 0xffffffffu);
  size_t base = ((size_t)b * NPTS + n) * KNN + sub;
  idx[base] = j;
  float rx = xsx[j] - qx;
  float ry = xsy[j] - qy;
  float rz = xsz[j] - qz;
  float rr2 = rx * rx + ry * ry + rz * rz + 1e-8f;
  float r = sqrtf(rr2);
  rl[base] = r;
  rhat[base * 3 + 0] = rx / r;
  rhat[base * 3 + 1] = ry / r;
  rhat[base * 3 + 2] = rz / r;
}

// ---------------------------------------------------------------- W convert+transpose (once)
__global__ __launch_bounds__(256) void k_wconv(
    const float* __restrict__ Wqkv, const float* __restrict__ Wo,
    _Float16* __restrict__ Whq, _Float16* __restrict__ Who)
{
  __shared__ _Float16 T[128][136];
  int m = blockIdx.x;
  const float* src; _Float16* dst;
  if (m < 48) { src = Wqkv + (size_t)m * 16384; dst = Whq + (size_t)m * 16384; }
  else { src = Wo + (size_t)(m - 48) * 16384; dst = Who + (size_t)(m - 48) * 16384; }
  int tid = threadIdx.x;
  for (int i = tid; i < 16384; i += 256) {
    int k = i >> 7, n = i & 127;
    T[n][k] = (_Float16)src[i];
  }
  __syncthreads();
  for (int i = tid; i < 16384; i += 256) {
    int n = i >> 7, k = i & 127;
    dst[i] = T[n][k];
  }
}

// ---------------------------------------------------------------- MFMA tile body (128x128x128)
#define MFMA_BODY(A_, ROWBASE_, WT_)                                          \
  const int tid  = threadIdx.x;                                               \
  const int lane = tid & 63;                                                  \
  const int w    = tid >> 6;                                                  \
  const int r15  = lane & 15;                                                 \
  const int g    = lane >> 4;                                                 \
  half8 bf[2][4];                                                             \
  _Pragma("unroll")                                                           \
  for (int ntl = 0; ntl < 2; ++ntl) {                                         \
    int n = (w * 2 + ntl) * 16 + r15;                                         \
    const _Float16* wp = (WT_) + (size_t)n * 128 + g * 8;                     \
    _Pragma("unroll")                                                         \
    for (int ks = 0; ks < 4; ++ks)                                            \
      bf[ntl][ks] = *(const half8*)(wp + ks * 32);                            \
  }                                                                           \
  {                                                                           \
    int r = tid >> 1;                                                         \
    const _Float16* src = (A_) + (size_t)((ROWBASE_) + r) * 128;              \
    int c0 = (tid & 1) * 8;                                                   \
    _Pragma("unroll")                                                         \
    for (int q = 0; q < 8; ++q) {                                             \
      int c = c0 + q;                                                         \
      *(uint4*)&As[r][c * 8] = *(const uint4*)(src + c * 8);                  \
    }                                                                         \
  }                                                                           \
  __syncthreads();                                                            \
  f32x4 acc[8][2] = {};                                                       \
  _Pragma("unroll")                                                           \
  for (int ks = 0; ks < 4; ++ks) {                                            \
    half8 a[8];                                                               \
    _Pragma("unroll")                                                         \
    for (int mt = 0; mt < 8; ++mt)                                            \
      a[mt] = *(const half8*)&As[mt * 16 + r15][ks * 32 + g * 8];             \
    _Pragma("unroll")                                                         \
    for (int mt = 0; mt < 8; ++mt) {                                          \
      acc[mt][0] = __builtin_amdgcn_mfma_f32_16x16x32_f16(a[mt], bf[0][ks], acc[mt][0], 0, 0, 0); \
      acc[mt][1] = __builtin_amdgcn_mfma_f32_16x16x32_f16(a[mt], bf[1][ks], acc[mt][1], 0, 0, 0); \
    }                                                                         \
  }

// ---------------------------------------------------------------- proj MFMA
__global__ __launch_bounds__(256) void k_proj_mfma(
    const _Float16* __restrict__ f0h, const _Float16* __restrict__ f1h,
    const _Float16* __restrict__ Wh, _Float16* __restrict__ P0,
    _Float16* __restrict__ P1, int nb0)
{
  __shared__ _Float16 As[128][136];
  int z = blockIdx.x;
  const _Float16* A; const _Float16* Wt; _Float16* P; int ldP, colBase, rowBase;
  if (z < nb0 * 5) {
    const int map0[5] = {0, 2, 4, 7, 9};
    int m = z / nb0, rb = z - m * nb0;
    A = f0h; rowBase = rb * 128;
    Wt = Wh + (size_t)map0[m] * 16384;
    P = P0; ldP = 640; colBase = m * 128;
  } else {
    z -= nb0 * 5;
    int nb1 = nb0 * 3;
    const int map1[7] = {1, 3, 5, 6, 8, 10, 11};
    int m = z / nb1, rb = z - m * nb1;
    A = f1h; rowBase = rb * 128;
    Wt = Wh + (size_t)map1[m] * 16384;
    P = P1; ldP = 896; colBase = m * 128;
  }
  MFMA_BODY(A, rowBase, Wt)
  #pragma unroll
  for (int mt = 0; mt < 8; ++mt) {
    #pragma unroll
    for (int ntl = 0; ntl < 2; ++ntl) {
      int col = colBase + (w * 2 + ntl) * 16 + r15;
      #pragma unroll
      for (int i = 0; i < 4; ++i) {
        int r = rowBase + mt * 16 + g * 4 + i;
        P[(size_t)r * ldP + col] = (_Float16)acc[mt][ntl][i];
      }
    }
  }
}

// ---------------------------------------------------------------- Wo MFMA + residual
__global__ __launch_bounds__(256) void k_wo_mfma(
    const _Float16* __restrict__ o0h, const _Float16* __restrict__ o1h,
    const _Float16* __restrict__ Who_l, const float* __restrict__ bo_l,
    float* __restrict__ f0, float* __restrict__ f1,
    _Float16* __restrict__ f0h, _Float16* __restrict__ f1h, int nb0)
{
  __shared__ _Float16 As[128][136];
  int z = blockIdx.x;
  const _Float16* A; const _Float16* Wt; const float* bias;
  float* F; _Float16* FH; int rowBase;
  if (z < nb0) {
    A = o0h; Wt = Who_l; bias = bo_l; F = f0; FH = f0h; rowBase = z * 128;
  } else {
    z -= nb0;
    A = o1h; Wt = Who_l + 16384; bias = bo_l + CC; F = f1; FH = f1h; rowBase = z * 128;
  }
  MFMA_BODY(A, rowBase, Wt)
  #pragma unroll
  for (int mt = 0; mt < 8; ++mt) {
    #pragma unroll
    for (int ntl = 0; ntl < 2; ++ntl) {
      int col = (w * 2 + ntl) * 16 + r15;
      float bv = bias[col];
      #pragma unroll
      for (int i = 0; i < 4; ++i) {
        int r = rowBase + mt * 16 + g * 4 + i;
        size_t p = (size_t)r * 128 + col;
        float val = F[p] + acc[mt][ntl][i] + bv;
        F[p] = val;
        FH[p] = (_Float16)val;
      }
    }
  }
}

// ---------------------------------------------------------------- attn v4
// 32 lanes per node (4 channels/lane), 8 nodes per 256-thread block,
// online softmax, 8-byte h4v gathers, fp16 output.
__global__ __launch_bounds__(256) void k_attn(
    const _Float16* __restrict__ P0, const _Float16* __restrict__ P1,
    const int* __restrict__ idx, const float* __restrict__ rhat,
    const float* __restrict__ rl,
    const float* __restrict__ Wr1, const float* __restrict__ br1,
    const float* __restrict__ Wr2, const float* __restrict__ br2,
    _Float16* __restrict__ o0h, _Float16* __restrict__ o1h,
    int nodeBase, int layer, int nbg)
{
  const int t = threadIdx.x;
  const int wv = t >> 5;            // node slot 0..7
  const int lane = t & 31;
  const int z = blockIdx.x;
  const int bb = z % nbg;
  const int qbase = (z / nbg) * 8;
  const int nodeLocal = bb * NPTS + qbase + wv;
  const int node = nodeBase + nodeLocal;
  const int batchRow = bb * NPTS;

  __shared__ float rn_s[8][KNN][80];
  __shared__ float hid_s[8][KNN][RH];
  __shared__ float rh_s[8][KNN][3];
  __shared__ float rl_s[8][KNN];

  // cooperative load of rhat/rl for the block's 8 nodes
  {
    int f = t;
    if (f < 192) {
      int nd = f / 24, e = f % 24;
      rh_s[nd][e / 3][e % 3] =
          rhat[((size_t)(nodeBase + bb * NPTS + qbase + nd)) * KNN * 3 + e];
    } else {
      int f2 = f - 192;
      int nd = f2 >> 3, k = f2 & 7;
      rl_s[nd][k] = rl[((size_t)(nodeBase + bb * NPTS + qbase + nd)) * KNN + k];
    }
  }
  __syncthreads();

  const float* wr1 = Wr1 + layer * RH;
  const float* wb1 = br1 + layer * RH;
  #pragma unroll
  for (int u = 0; u < 8; ++u) {
    int f = u * 256 + t;            // 2048 = 8 nodes * KNN * RH
    int nd = f >> 8, k = (f >> 5) & 7, i = f & 31;
    float zv = rl_s[nd][k] * wr1[i] + wb1[i];
    hid_s[nd][k][i] = zv / (1.0f + expf(-zv));
  }
  __syncthreads();
  const float* wr2 = Wr2 + layer * RH * 80;
  const float* wb2 = br2 + layer * 80;
  #pragma unroll
  for (int u = 0; u < 20; ++u) {
    int f = u * 256 + t;            // 5120 = 8 nodes * KNN * 80
    int nd = f / 640, rem = f - nd * 640;
    int k = rem / 80, col = rem - k * 80;
    float acc = wb2[col];
    #pragma unroll
    for (int i = 0; i < RH; ++i) acc += hid_s[nd][k][i] * wr2[i * 80 + col];
    rn_s[nd][k][col] = acc;
  }
  __syncthreads();

  const int c0 = lane * 4;
  const int h = lane >> 2;
  const _Float16* p0n = P0 + (size_t)nodeLocal * 640 + c0;
  const _Float16* p1n = P1 + (size_t)nodeLocal * 2688 + c0;
  h4v q0v  = *(const h4v*)(p0n);
  h4v q1xv = *(const h4v*)(p1n);
  h4v q1yv = *(const h4v*)(p1n + 896);
  h4v q1zv = *(const h4v*)(p1n + 1792);

  const float inv_scale = 0.17677669529663687f;  // 1/sqrt(32)
  const int* idxp = idx + (size_t)node * KNN;
  int jls[KNN];
  #pragma unroll
  for (int k = 0; k < KNN; ++k) jls[k] = batchRow + idxp[k];

  float m = -3.0e38f, ssum = 0.0f;
  float a0[4] = {}, ax[4] = {}, ay[4] = {}, az[4] = {};

  for (int k = 0; k < KNN; ++k) {
    int jl = jls[k];
    const _Float16* g0 = P0 + (size_t)jl * 640 + c0;
    const _Float16* g1 = P1 + (size_t)jl * 2688 + c0;
    float rx = rh_s[wv][k][0], ry = rh_s[wv][k][1], rz = rh_s[wv][k][2];

    h4v G02 = *(const h4v*)(g0 + 128), G04 = *(const h4v*)(g0 + 256);
    h4v G07 = *(const h4v*)(g0 + 384), G09 = *(const h4v*)(g0 + 512);
    h4v G13x = *(const h4v*)(g1 + 128),  G13y = *(const h4v*)(g1 + 896 + 128),  G13z = *(const h4v*)(g1 + 1792 + 128);
    h4v G15x = *(const h4v*)(g1 + 256),  G15y = *(const h4v*)(g1 + 896 + 256),  G15z = *(const h4v*)(g1 + 1792 + 256);
    h4v G16x = *(const h4v*)(g1 + 384),  G16y = *(const h4v*)(g1 + 896 + 384),  G16z = *(const h4v*)(g1 + 1792 + 384);
    h4v G18x = *(const h4v*)(g1 + 512),  G18y = *(const h4v*)(g1 + 896 + 512),  G18z = *(const h4v*)(g1 + 1792 + 512);
    h4v G1Ax = *(const h4v*)(g1 + 640),  G1Ay = *(const h4v*)(g1 + 896 + 640),  G1Az = *(const h4v*)(g1 + 1792 + 640);
    h4v G1Bx = *(const h4v*)(g1 + 768),  G1By = *(const h4v*)(g1 + 896 + 768),  G1Bz = *(const h4v*)(g1 + 1792 + 768);

    const float* rnh = &rn_s[wv][k][h * 10];
    float r0 = rnh[0], r1 = rnh[1], r2 = rnh[2], r3 = rnh[3], r4 = rnh[4];
    float r5 = rnh[5], r6 = rnh[6], r7 = rnh[7], r8 = rnh[8], r9 = rnh[9];

    float pl = 0.0f;
    float v0c[4], vxc[4], vyc[4], vzc[4];
    #pragma unroll
    for (int ci = 0; ci < 4; ++ci) {
      float g02 = (float)G02[ci], g04 = (float)G04[ci];
      float g07 = (float)G07[ci], g09 = (float)G09[ci];
      float g13x = (float)G13x[ci], g13y = (float)G13y[ci], g13z = (float)G13z[ci];
      float g15x = (float)G15x[ci], g15y = (float)G15y[ci], g15z = (float)G15z[ci];
      float g16x = (float)G16x[ci], g16y = (float)G16y[ci], g16z = (float)G16z[ci];
      float g18x = (float)G18x[ci], g18y = (float)G18y[ci], g18z = (float)G18z[ci];
      float g1ax = (float)G1Ax[ci], g1ay = (float)G1Ay[ci], g1az = (float)G1Az[ci];
      float g1bx = (float)G1Bx[ci], g1by = (float)G1By[ci], g1bz = (float)G1Bz[ci];

      float DP3 = g13x * rx + g13y * ry + g13z * rz;
      float DP6 = g16x * rx + g16y * ry + g16z * rz;
      float DP8 = g18x * rx + g18y * ry + g18z * rz;
      float DPB = g1bx * rx + g1by * ry + g1bz * rz;

      float k0  = g02 * r0 + DP3 * r1;
      float k1x = g04 * rx * r2 + g15x * r3 + (3.0f * rx * DP6 - g16x) * r4;
      float k1y = g04 * ry * r2 + g15y * r3 + (3.0f * ry * DP6 - g16y) * r4;
      float k1z = g04 * rz * r2 + g15z * r3 + (3.0f * rz * DP6 - g16z) * r4;
      v0c[ci] = g07 * r5 + DP8 * r6;
      vxc[ci] = g09 * rx * r7 + g1ax * r8 + (3.0f * rx * DPB - g1bx) * r9;
      vyc[ci] = g09 * ry * r7 + g1ay * r8 + (3.0f * ry * DPB - g1by) * r9;
      vzc[ci] = g09 * rz * r7 + g1az * r8 + (3.0f * rz * DPB - g1bz) * r9;

      pl += (float)q0v[ci] * k0 + (float)q1xv[ci] * k1x
          + (float)q1yv[ci] * k1y + (float)q1zv[ci] * k1z;
    }
    pl += __shfl_xor(pl, 1, 4);
    pl += __shfl_xor(pl, 2, 4);
    pl *= inv_scale;

    float mnew = fmaxf(m, pl);
    float scale = expf(m - mnew);
    float wgt = expf(pl - mnew);
    ssum = ssum * scale + wgt;
    #pragma unroll
    for (int ci = 0; ci < 4; ++ci) {
      a0[ci] = a0[ci] * scale + wgt * v0c[ci];
      ax[ci] = ax[ci] * scale + wgt * vxc[ci];
      ay[ci] = ay[ci] * scale + wgt * vyc[ci];
      az[ci] = az[ci] * scale + wgt * vzc[ci];
    }
    m = mnew;
  }

  float invs = 1.0f / ssum;
  h4v o;
  #pragma unroll
  for (int ci = 0; ci < 4; ++ci) o[ci] = (_Float16)(a0[ci] * invs);
  *(h4v*)(o0h + (size_t)nodeLocal * 128 + c0) = o;
  #pragma unroll
  for (int ci = 0; ci < 4; ++ci) o[ci] = (_Float16)(ax[ci] * invs);
  *(h4v*)(o1h + ((size_t)nodeLocal * 3 + 0) * 128 + c0) = o;
  #pragma unroll
  for (int ci = 0; ci < 4; ++ci) o[ci] = (_Float16)(ay[ci] * invs);
  *(h4v*)(o1h + ((size_t)nodeLocal * 3 + 1) * 128 + c0) = o;
  #pragma unroll
  for (int ci = 0; ci < 4; ++ci) o[ci] = (_Float16)(az[ci] * invs);
  *(h4v*)(o1h + ((size_t)nodeLocal * 3 + 2) * 128 + c0) = o;
}

// ---------------------------------------------------------------- final out
__global__ __launch_bounds__(256) void k_out(
    const float* __restrict__ f1, const float* __restrict__ Wout,
    const float* __restrict__ bout, float* __restrict__ out)
{
  int i = blockIdx.x * 256 + threadIdx.x;
  int v = i % 3;
  const float* row = f1 + (size_t)i * CC;
  const float* w = Wout + v * CC;
  float acc = 0.0f;
  #pragma unroll
  for (int c = 0; c < CC; c += 4) {
    float4 fv = *(const float4*)&row[c];
    float4 wv = *(const float4*)&w[c];
    acc += fv.x * wv.x + fv.y * wv.y + fv.z * wv.z + fv.w * wv.w;
  }
  out[i] = acc + bout[v];
}

// ---------------------------------------------------------------- host
extern "C" void kernel_launch(void* const* d_in, const int* in_sizes, int n_in,
                              void* d_out, int out_size, void* d_ws, size_t ws_size,
                              hipStream_t stream) {
  const float* x    = (const float*)d_in[0];
  const float* t    = (const float*)d_in[2];
  const float* Wt1  = (const float*)d_in[3];
  const float* bt1  = (const float*)d_in[4];
  const float* Wt2  = (const float*)d_in[5];
  const float* bt2  = (const float*)d_in[6];
  const float* Win0 = (const float*)d_in[7];
  const float* bin0 = (const float*)d_in[8];
  const float* Win1 = (const float*)d_in[9];
  const float* Wqkv = (const float*)d_in[10];
  const float* Wr1  = (const float*)d_in[11];
  const float* br1  = (const float*)d_in[12];
  const float* Wr2  = (const float*)d_in[13];
  const float* br2  = (const float*)d_in[14];
  const float* Wo   = (const float*)d_in[15];
  const float* bo   = (const float*)d_in[16];
  const float* Wout = (const float*)d_in[17];
  const float* bout = (const float*)d_in[18];
  float* out = (float*)d_out;

  char* wsb = (char*)d_ws;
  size_t off = 0;
  auto alloc = [&](size_t bytes) -> void* {
    void* p = wsb + off;
    off = (off + bytes + 255) & ~(size_t)255;
    return p;
  };
  const int totalNodes = NBATCH * NPTS;  // 8192
  float* pre0 = (float*)alloc((size_t)NBATCH * CC * 4);
  float* f0   = (float*)alloc((size_t)totalNodes * CC * 4);
  float* f1   = (float*)alloc((size_t)totalNodes * 3 * CC * 4);
  _Float16* f0h = (_Float16*)alloc((size_t)totalNodes * CC * 2);
  _Float16* f1h = (_Float16*)alloc((size_t)totalNodes * 3 * CC * 2);
  _Float16* Whq = (_Float16*)alloc((size_t)NL * 12 * CC * HD_ * 2);
  _Float16* Who = (_Float16*)alloc((size_t)NL * 2 * CC * HD_ * 2);
  int*   idx  = (int*)alloc((size_t)totalNodes * KNN * 4);
  float* rhat = (float*)alloc((size_t)totalNodes * KNN * 3 * 4);
  float* rl   = (float*)alloc((size_t)totalNodes * KNN * 4);
  size_t fixedBytes = off;
  size_t perBatch = (size_t)NPTS * ((640 + 2688) * 2 + (128 + 384) * 2);
  int nbg = 8;
  while (nbg > 1 && fixedBytes + (size_t)nbg * perBatch + 8192 > ws_size) nbg >>= 1;
  _Float16* P0  = (_Float16*)alloc((size_t)nbg * NPTS * 640 * 2);
  _Float16* P1  = (_Float16*)alloc((size_t)nbg * NPTS * 2688 * 2);
  _Float16* o0h = (_Float16*)alloc((size_t)nbg * NPTS * 128 * 2);
  _Float16* o1h = (_Float16*)alloc((size_t)nbg * NPTS * 384 * 2);

  k_temb<<<NBATCH, 128, 0, stream>>>(t, Wt1, bt1, Wt2, bt2, Win0, bin0, pre0);
  k_init<<<totalNodes / 2, 256, 0, stream>>>(x, Win0, Win1, pre0, f0, f1, f0h, f1h);
  k_knn<<<NBATCH * 32, 256, 0, stream>>>(x, idx, rhat, rl);
  k_wconv<<<56, 256, 0, stream>>>(Wqkv, Wo, Whq, Who);

  for (int g = 0; g < NBATCH / nbg; ++g) {
    int nodeBase = g * nbg * NPTS;
    int nodes = nbg * NPTS;
    int nb0 = nodes / 128;
    for (int l = 0; l < NL; ++l) {
      k_proj_mfma<<<nb0 * 26, 256, 0, stream>>>(
          f0h + (size_t)nodeBase * CC, f1h + (size_t)nodeBase * 3 * CC,
          Whq + (size_t)l * 12 * CC * HD_, P0, P1, nb0);
      k_attn<<<nodes / 8, 256, 0, stream>>>(
          P0, P1, idx, rhat, rl, Wr1, br1, Wr2, br2, o0h, o1h, nodeBase, l, nbg);
      k_wo_mfma<<<nb0 * 4, 256, 0, stream>>>(
          o0h, o1h, Who + (size_t)l * 2 * CC * HD_, bo + (size_t)(l * 2) * CC,
          f0 + (size_t)nodeBase * CC, f1 + (size_t)nodeBase * 3 * CC,
          f0h + (size_t)nodeBase * CC, f1h + (size_t)nodeBase * 3 * CC, nb0);
    }
  }
  k_out<<<(totalNodes * 3) / 256, 256, 0, stream>>>(f1, Wout, bout, out);
}